// Round 11
// baseline (497.133 us; speedup 1.0000x reference)
//
#include <hip/hip_runtime.h>
#include <hip/hip_bf16.h>

#define SLEN 512
#define BATCH 256
#define NIN 300
#define KP 320
#define NG 256
#define NH 64
#define BM 128
#define BN 128
#define BK 64
#define LDP 72     // gemm LDS pad
#define RB 16      // batch rows per rec block
#define HROW 72    // h tile row stride (f16): 144B -> 2-way (free) conflicts
#define HMSZ (RB * HROW)

typedef float f32x4 __attribute__((ext_vector_type(4)));
typedef short s16x8 __attribute__((ext_vector_type(8)));
typedef short s16x4 __attribute__((ext_vector_type(4)));
typedef _Float16 f16x8 __attribute__((ext_vector_type(8)));
typedef _Float16 f16x4 __attribute__((ext_vector_type(4)));

__device__ __forceinline__ short f2bf(float f) {
  union { float f; unsigned u; } v; v.f = f;
  unsigned r = v.u + 0x7fffu + ((v.u >> 16) & 1u);  // RNE
  return (short)(r >> 16);
}

// WcatT[n][k] (bf16, K padded to 320), bcat[n], Wg16[col][k] = f16(W_glt[k][col]).
__global__ void prep_w(const float* __restrict__ Wpt0, const float* __restrict__ bpt0,
                       const float* __restrict__ Wpt1, const float* __restrict__ bpt1,
                       const float* __restrict__ Wglt,
                       short* __restrict__ WcatT, float* __restrict__ bcat,
                       _Float16* __restrict__ Wg16) {
  int idx = blockIdx.x * 256 + threadIdx.x;
  if (idx < NG * KP) {
    int n = idx / KP, k = idx - n * KP;
    int g = n >> 6, h = n & 63;
    float w = 0.f;
    if (k < NIN) {
      if (h < 32) w = Wpt0[k * 128 + g * 32 + h];
      else        w = 0.5f * Wpt1[(k >> 1) * 128 + g * 32 + (h - 32)];
    }
    WcatT[idx] = f2bf(w);
  }
  if (idx < NG * NH) {
    int c = idx >> 6, k = idx & 63;
    Wg16[idx] = (_Float16)Wglt[k * NG + c];
  }
  if (idx < NG) {
    int g = idx >> 6, h = idx & 63;
    bcat[idx] = (h < 32) ? bpt0[g * 32 + h] : bpt1[g * 32 + h - 32];
  }
}

// Ct[step][col][b] = f16( bf16(x[row]) @ WcatT^T + bcat ),  row = step*256 + b
__global__ __launch_bounds__(256) void gemm_i2h(
    const float* __restrict__ x, const short* __restrict__ WcatT,
    const float* __restrict__ bcat, _Float16* __restrict__ Ct) {
  __shared__ short As[BM][LDP];
  __shared__ short Bs[BN][LDP];
  const int tid = threadIdx.x;
  const int m0 = blockIdx.x * BM;
  const int n0 = blockIdx.y * BN;
  const int lane = tid & 63;
  const int w = tid >> 6;
  const int wr = w >> 1, wc = w & 1;

  f32x4 acc[4][4];
#pragma unroll
  for (int m = 0; m < 4; ++m)
#pragma unroll
    for (int n = 0; n < 4; ++n) acc[m][n] = (f32x4){0.f, 0.f, 0.f, 0.f};

  const int arow_l = tid >> 4;
  const int acol   = (tid & 15) * 4;
  const int brow_l = tid >> 3;
  const int bcol   = (tid & 7) * 8;

  for (int k0 = 0; k0 < KP; k0 += BK) {
#pragma unroll
    for (int p = 0; p < 8; ++p) {
      int row = p * 16 + arow_l;
      int gk = k0 + acol;
      f32x4 v = (f32x4){0.f, 0.f, 0.f, 0.f};
      if (gk + 3 < NIN)
        v = *reinterpret_cast<const f32x4*>(&x[(size_t)(m0 + row) * NIN + gk]);
      s16x4 sv;
      sv[0] = f2bf(v[0]); sv[1] = f2bf(v[1]); sv[2] = f2bf(v[2]); sv[3] = f2bf(v[3]);
      *reinterpret_cast<s16x4*>(&As[row][acol]) = sv;
    }
#pragma unroll
    for (int p = 0; p < 4; ++p) {
      int n = p * 32 + brow_l;
      s16x8 v = *reinterpret_cast<const s16x8*>(&WcatT[(size_t)(n0 + n) * KP + k0 + bcol]);
      *reinterpret_cast<s16x8*>(&Bs[n][bcol]) = v;
    }
    __syncthreads();
#pragma unroll
    for (int ks = 0; ks < 2; ++ks) {
      const int kk = ks * 32 + (lane >> 4) * 8;
      s16x8 a[4], b[4];
#pragma unroll
      for (int m = 0; m < 4; ++m)
        a[m] = *reinterpret_cast<const s16x8*>(&As[wr * 64 + m * 16 + (lane & 15)][kk]);
#pragma unroll
      for (int n = 0; n < 4; ++n)
        b[n] = *reinterpret_cast<const s16x8*>(&Bs[wc * 64 + n * 16 + (lane & 15)][kk]);
#pragma unroll
      for (int m = 0; m < 4; ++m)
#pragma unroll
        for (int n = 0; n < 4; ++n)
          acc[m][n] = __builtin_amdgcn_mfma_f32_16x16x32_bf16(a[m], b[n], acc[m][n], 0, 0, 0);
    }
    __syncthreads();
  }
  const int fc = lane & 15;
  const int fr = (lane >> 4) * 4;
#pragma unroll
  for (int n = 0; n < 4; ++n) {
    int col = n0 + wc * 64 + n * 16 + fc;
    float bias = bcat[col];
#pragma unroll
    for (int m = 0; m < 4; ++m) {
      int row0 = m0 + wr * 64 + m * 16 + fr;     // 4 consecutive rows, no 256-cross
      int stp = row0 >> 8, bb = row0 & 255;
      f16x4 hv;
#pragma unroll
      for (int r = 0; r < 4; ++r) hv[r] = (_Float16)(acc[m][n][r] + bias);
      *reinterpret_cast<f16x4*>(&Ct[((size_t)stp * NG + col) * BATCH + bb]) = hv;
    }
  }
}

// MFMA recurrence: one block = 16 batch rows, 4 waves. Wave ww owns units
// [16ww,16ww+16); lane: unit u = 16ww+(l&15), rows R0..R0+3, R0=(l>>4)*4.
// Per step: 8x mfma_16x16x32_f16 (4 gate tiles x 2 K-halves); C-frag places
// f,g,i,o for each (row,unit) IN-LANE -> no shuffles; h exchanged via a
// 72-padded double-buffered LDS tile; ONE barrier/step. B-frags (32 VGPRs)
// are pinned by an OPAQUE-base LDS alias (asm-hidden offset -> every h write
// may-alias all of LDS -> weight-load remat illegal; fixes r7-r10's demotion).
__global__ __launch_bounds__(256, 4)
void rec_seq(
    const _Float16* __restrict__ i2h, const _Float16* __restrict__ Wg16,
    const float* __restrict__ h_in, const float* __restrict__ c_in,
    float* __restrict__ h_state, float* __restrict__ c_state,
    float* __restrict__ hs_out, float* __restrict__ hT_out, float* __restrict__ cT_out,
    int T, int is_last) {
  const int blk = blockIdx.x;
  const int tid = threadIdx.x;
  const int ww = tid >> 6;
  const int l = tid & 63;
  const int lf = l & 15;
  const int qq = l >> 4;
  const int u = ww * 16 + lf;
  const int R0 = qq * 4;
  const int brow = blk * RB;

  __shared__ __align__(16) char LB[2048 * 16];
  f16x8* Wst = reinterpret_cast<f16x8*>(LB);

  unsigned hoff = 0;
  asm volatile("" : "+s"(hoff));                       // opaque 0
  _Float16* hm = reinterpret_cast<_Float16*>(LB + hoff);

  for (int e = tid; e < 2048; e += 256)
    Wst[e] = *reinterpret_cast<const f16x8*>(Wg16 + (size_t)e * 8);
  __syncthreads();

  // B-frags: tile g, K-half ks -> Wst[(g*64+u)*8 + ks*4 + qq]
  f16x8 wF0 = Wst[(0 * 64 + u) * 8 + qq], wF1 = Wst[(0 * 64 + u) * 8 + 4 + qq];
  f16x8 wG0 = Wst[(1 * 64 + u) * 8 + qq], wG1 = Wst[(1 * 64 + u) * 8 + 4 + qq];
  f16x8 wI0 = Wst[(2 * 64 + u) * 8 + qq], wI1 = Wst[(2 * 64 + u) * 8 + 4 + qq];
  f16x8 wO0 = Wst[(3 * 64 + u) * 8 + qq], wO1 = Wst[(3 * 64 + u) * 8 + 4 + qq];

  f32x4 cc, hh;
#pragma unroll
  for (int r = 0; r < 4; ++r) {
    cc[r] = c_in[(size_t)(brow + R0 + r) * NH + u];
    hh[r] = 0.f;
  }
  __syncthreads();   // all Wst reads complete before hm overwrite

  for (int e = tid; e < RB * NH; e += 256) {
    int rr = e >> 6, uu = e & 63;
    hm[rr * HROW + uu] = (_Float16)h_in[(size_t)(brow + rr) * NH + uu];
  }
  asm volatile("s_waitcnt lgkmcnt(0)" ::: "memory");
  __syncthreads();

  const size_t ST16 = (size_t)NG * BATCH;        // i2h f16 per step
  const size_t HSST = (size_t)BATCH * NH;        // hs f32 per step
  const _Float16* ipF = i2h + (size_t)(0 * 64 + u) * BATCH + brow + R0;
  const _Float16* ipG = i2h + (size_t)(1 * 64 + u) * BATCH + brow + R0;
  const _Float16* ipI = i2h + (size_t)(2 * 64 + u) * BATCH + brow + R0;
  const _Float16* ipO = i2h + (size_t)(3 * 64 + u) * BATCH + brow + R0;
  float* hp = hs_out + (size_t)(brow + R0) * NH + u;

#define ACT1(SD, X, MUL, CL) { \
    float xx_ = fminf(fmaxf((X), -(CL)), (CL)); \
    float ee_ = __expf(-(MUL) * xx_); \
    SD = __builtin_amdgcn_rcpf(1.f + ee_); }

#define MF(A, B, C) __builtin_amdgcn_mfma_f32_16x16x32_f16(A, B, C, 0, 0, 0)

#define STEP(CF, CG, CI, CO, PAR) { \
    const _Float16* hb = hm + (PAR) * HMSZ; \
    f16x8 a0 = *reinterpret_cast<const f16x8*>(hb + lf * HROW + qq * 8); \
    f16x8 a1 = *reinterpret_cast<const f16x8*>(hb + lf * HROW + 32 + qq * 8); \
    f32x4 z4 = (f32x4){0.f, 0.f, 0.f, 0.f}; \
    f32x4 aF = MF(a1, wF1, MF(a0, wF0, z4)); \
    f32x4 aG = MF(a1, wG1, MF(a0, wG0, z4)); \
    f32x4 aI = MF(a1, wI1, MF(a0, wI0, z4)); \
    f32x4 aO = MF(a1, wO1, MF(a0, wO0, z4)); \
    _Float16* hw = hm + (1 - (PAR)) * HMSZ + R0 * HROW + u; \
    _Pragma("unroll") \
    for (int r = 0; r < 4; ++r) { \
      float pf = aF[r] + (float)(CF)[r]; \
      float pg = aG[r] + (float)(CG)[r]; \
      float pi = aI[r] + (float)(CI)[r]; \
      float po = aO[r] + (float)(CO)[r]; \
      float sf_, sg2, si_, so_; \
      ACT1(sf_, pf, 1.f, 30.f) ACT1(sg2, pg, 2.f, 15.f) \
      ACT1(si_, pi, 1.f, 30.f) ACT1(so_, po, 1.f, 30.f) \
      float tg = 2.f * sg2 - 1.f; \
      float c1 = sf_ * cc[r] + si_ * tg; cc[r] = c1; \
      float st2; ACT1(st2, c1, 2.f, 15.f) \
      float th = 2.f * st2 - 1.f; \
      float h1 = so_ * th; hh[r] = h1; \
      hw[r * HROW] = (_Float16)h1; \
      hp[(size_t)r * NH] = h1; \
    } \
    hp += HSST; \
    asm volatile("s_waitcnt lgkmcnt(0)" ::: "memory"); \
    __builtin_amdgcn_s_barrier(); }

#define LDG(PF, PG, PI, PO, S) { size_t o_ = (size_t)(S) * ST16; \
    PF = *reinterpret_cast<const f16x4*>(ipF + o_); \
    PG = *reinterpret_cast<const f16x4*>(ipG + o_); \
    PI = *reinterpret_cast<const f16x4*>(ipI + o_); \
    PO = *reinterpret_cast<const f16x4*>(ipO + o_); }

  int s = 0;
  if (T >= 4) {
    f16x4 c0F, c0G, c0I, c0O, c1F, c1G, c1I, c1O;
    f16x4 n0F, n0G, n0I, n0O, n1F, n1G, n1I, n1O;
    LDG(c0F, c0G, c0I, c0O, 0) LDG(c1F, c1G, c1I, c1O, 1)
    LDG(n0F, n0G, n0I, n0O, 2) LDG(n1F, n1G, n1I, n1O, 3)
    while (s + 2 <= T) {
      f16x4 f0F = c0F, f0G = c0G, f0I = c0I, f0O = c0O;
      f16x4 f1F = c1F, f1G = c1G, f1I = c1I, f1O = c1O;
      if (s + 4 < T) LDG(f0F, f0G, f0I, f0O, s + 4)
      if (s + 5 < T) LDG(f1F, f1G, f1I, f1O, s + 5)
      STEP(c0F, c0G, c0I, c0O, 0)
      STEP(c1F, c1G, c1I, c1O, 1)
      c0F = n0F; c0G = n0G; c0I = n0I; c0O = n0O;
      c1F = n1F; c1G = n1G; c1I = n1I; c1O = n1O;
      n0F = f0F; n0G = f0G; n0I = f0I; n0O = f0O;
      n1F = f1F; n1G = f1G; n1I = f1I; n1O = f1O;
      s += 2;
    }
    if (s < T) { STEP(c0F, c0G, c0I, c0O, 0) s++; }
  } else {
    while (s < T) {
      f16x4 cF, cG, cI, cO;
      LDG(cF, cG, cI, cO, s)
      if (s & 1) { STEP(cF, cG, cI, cO, 1) }
      else       { STEP(cF, cG, cI, cO, 0) }
      s++;
    }
  }

#pragma unroll
  for (int r = 0; r < 4; ++r) {
    h_state[(size_t)(brow + R0 + r) * NH + u] = hh[r];
    c_state[(size_t)(brow + R0 + r) * NH + u] = cc[r];
    if (is_last) {
      hT_out[(size_t)(brow + R0 + r) * NH + u] = hh[r];
      cT_out[(size_t)(brow + R0 + r) * NH + u] = cc[r];
    }
  }
}

// decoded[idx][j] = hs[idx][:] @ Wdec[:,j] + bdec[j], idx = s*BATCH+b
__global__ __launch_bounds__(256) void decode(
    const float* __restrict__ hs, const float* __restrict__ Wdec,
    const float* __restrict__ bdec, float* __restrict__ out, int n) {
  __shared__ float wl[NH * 3];
  __shared__ float bl[3];
  const int tid = threadIdx.x;
  if (tid < NH * 3) wl[tid] = Wdec[tid];
  if (tid < 3) bl[tid] = bdec[tid];
  __syncthreads();
  int idx = blockIdx.x * 256 + tid;
  if (idx >= n) return;
  const float* hp = hs + (size_t)idx * NH;
  float d0 = 0.f, d1 = 0.f, d2 = 0.f;
#pragma unroll
  for (int k = 0; k < NH; k += 4) {
    f32x4 h4 = *reinterpret_cast<const f32x4*>(&hp[k]);
#pragma unroll
    for (int j = 0; j < 4; ++j) {
      d0 += h4[j] * wl[(k + j) * 3 + 0];
      d1 += h4[j] * wl[(k + j) * 3 + 1];
      d2 += h4[j] * wl[(k + j) * 3 + 2];
    }
  }
  out[(size_t)idx * 3 + 0] = d0 + bl[0];
  out[(size_t)idx * 3 + 1] = d1 + bl[1];
  out[(size_t)idx * 3 + 2] = d2 + bl[2];
}

extern "C" void kernel_launch(void* const* d_in, const int* in_sizes, int n_in,
                              void* d_out, int out_size, void* d_ws, size_t ws_size,
                              hipStream_t stream) {
  const float* x    = (const float*)d_in[0];
  const float* h0   = (const float*)d_in[1];
  const float* c0   = (const float*)d_in[2];
  const float* Wpt0 = (const float*)d_in[3];
  const float* bpt0 = (const float*)d_in[4];
  const float* Wpt1 = (const float*)d_in[5];
  const float* bpt1 = (const float*)d_in[6];
  const float* Wglt = (const float*)d_in[7];
  const float* Wdec = (const float*)d_in[8];
  const float* bdec = (const float*)d_in[9];
  float* out = (float*)d_out;

  char* ws = (char*)d_ws;
  short*     WcatT   = (short*)(ws);              // 163840 B
  float*     bcat    = (float*)(ws + 163840);     // 1 KB
  _Float16*  Wg16    = (_Float16*)(ws + 164864);  // 32768 B
  float*     h_state = (float*)(ws + 197632);     // 64 KB
  float*     c_state = (float*)(ws + 263168);     // 64 KB
  const size_t base = 328704;

  // per-step chunk bytes: i2h f16 (256*256*2) + hs f32 (256*64*4)
  const size_t i2h_step = (size_t)BATCH * NG * 2;
  const size_t hs_step  = (size_t)BATCH * NH * 4;
  size_t avail = (ws_size > base) ? ws_size - base : 0;
  int T = (int)(avail / (i2h_step + hs_step));
  if (T > SLEN) T = SLEN;
  if (T < 1) T = 1;

  _Float16* i2h = (_Float16*)(ws + base);
  float*    hs  = (float*)(ws + base + (size_t)T * i2h_step);

  prep_w<<<dim3((NG * KP + 255) / 256), dim3(256), 0, stream>>>(
      Wpt0, bpt0, Wpt1, bpt1, Wglt, WcatT, bcat, Wg16);

  for (int t0 = 0; t0 < SLEN; t0 += T) {
    int Tc = (SLEN - t0 < T) ? (SLEN - t0) : T;
    dim3 g(Tc * BATCH / BM, NG / BN);
    gemm_i2h<<<g, dim3(256), 0, stream>>>(
        x + (size_t)t0 * BATCH * NIN, WcatT, bcat, i2h);
    rec_seq<<<dim3(BATCH / RB), dim3(256), 0, stream>>>(
        i2h, Wg16,
        (t0 == 0) ? h0 : h_state, (t0 == 0) ? c0 : c_state,
        h_state, c_state, hs,
        out + (size_t)SLEN * BATCH * 3,
        out + (size_t)SLEN * BATCH * 3 + BATCH * NH,
        Tc, (t0 + Tc >= SLEN) ? 1 : 0);
    decode<<<dim3((Tc * BATCH + 255) / 256), dim3(256), 0, stream>>>(
        hs, Wdec, bdec, out + (size_t)t0 * BATCH * 3, Tc * BATCH);
  }
}

// Round 12
// 403.800 us; speedup vs baseline: 1.2311x; 1.2311x over previous
//
#include <hip/hip_runtime.h>
#include <hip/hip_bf16.h>

#define SLEN 512
#define BATCH 256
#define NIN 300
#define KP 320
#define NG 256
#define NH 64
#define BM 128
#define BN 128
#define BK 64
#define LDP 72   // padded LDS row length (bf16) -> 144B rows, 2-way (free) b128 reads

typedef float f32x4 __attribute__((ext_vector_type(4)));
typedef short s16x8 __attribute__((ext_vector_type(8)));
typedef short s16x4 __attribute__((ext_vector_type(4)));
typedef _Float16 f16x8 __attribute__((ext_vector_type(8)));
typedef _Float16 f16x4 __attribute__((ext_vector_type(4)));

__device__ __forceinline__ short f2bf(float f) {
  union { float f; unsigned u; } v; v.f = f;
  unsigned r = v.u + 0x7fffu + ((v.u >> 16) & 1u);  // RNE
  return (short)(r >> 16);
}

// Build WcatT[n][k] (bf16, K padded to 320), bcat[n], and Wg16[col][k] = f16(W_glt[k][col]).
__global__ void prep_w(const float* __restrict__ Wpt0, const float* __restrict__ bpt0,
                       const float* __restrict__ Wpt1, const float* __restrict__ bpt1,
                       const float* __restrict__ Wglt,
                       short* __restrict__ WcatT, float* __restrict__ bcat,
                       _Float16* __restrict__ Wg16) {
  int idx = blockIdx.x * 256 + threadIdx.x;
  if (idx < NG * KP) {
    int n = idx / KP, k = idx - n * KP;
    int g = n >> 6, h = n & 63;
    float w = 0.f;
    if (k < NIN) {
      if (h < 32) w = Wpt0[k * 128 + g * 32 + h];
      else        w = 0.5f * Wpt1[(k >> 1) * 128 + g * 32 + (h - 32)];
    }
    WcatT[idx] = f2bf(w);
  }
  if (idx < NG * NH) {  // transpose W_glt (64 x 256) -> Wg16 (256 x 64), f16
    int c = idx >> 6, k = idx & 63;
    Wg16[idx] = (_Float16)Wglt[k * NG + c];
  }
  if (idx < NG) {
    int g = idx >> 6, h = idx & 63;
    bcat[idx] = (h < 32) ? bpt0[g * 32 + h] : bpt1[g * 32 + h - 32];
  }
}

// C[row][n] = f16( bf16(x[row]) @ WcatT^T + bcat )
// grid = (2, M/BM): the two N-halves of one M-tile are dispatch-adjacent ->
// the second reads the x slab from L2 instead of HBM (was 2x157 MB).
__global__ __launch_bounds__(256) void gemm_i2h(
    const float* __restrict__ x, const short* __restrict__ WcatT,
    const float* __restrict__ bcat, _Float16* __restrict__ C) {
  __shared__ short As[BM][LDP];
  __shared__ short Bs[BN][LDP];
  const int tid = threadIdx.x;
  const int m0 = blockIdx.y * BM;     // swapped: M on the slow axis
  const int n0 = blockIdx.x * BN;     // N-pair adjacent in dispatch order
  const int lane = tid & 63;
  const int w = tid >> 6;
  const int wr = w >> 1, wc = w & 1;

  f32x4 acc[4][4];
#pragma unroll
  for (int m = 0; m < 4; ++m)
#pragma unroll
    for (int n = 0; n < 4; ++n) acc[m][n] = (f32x4){0.f, 0.f, 0.f, 0.f};

  const int arow_l = tid >> 4;        // 0..15
  const int acol   = (tid & 15) * 4;  // 0..60
  const int brow_l = tid >> 3;        // 0..31
  const int bcol   = (tid & 7) * 8;   // 0..56

  for (int k0 = 0; k0 < KP; k0 += BK) {
#pragma unroll
    for (int p = 0; p < 8; ++p) {
      int row = p * 16 + arow_l;
      int gk = k0 + acol;
      f32x4 v = (f32x4){0.f, 0.f, 0.f, 0.f};
      if (gk + 3 < NIN)  // 300 = 4*75 so vectors never straddle the boundary
        v = *reinterpret_cast<const f32x4*>(&x[(size_t)(m0 + row) * NIN + gk]);
      s16x4 sv;
      sv[0] = f2bf(v[0]); sv[1] = f2bf(v[1]); sv[2] = f2bf(v[2]); sv[3] = f2bf(v[3]);
      *reinterpret_cast<s16x4*>(&As[row][acol]) = sv;
    }
#pragma unroll
    for (int p = 0; p < 4; ++p) {
      int n = p * 32 + brow_l;
      s16x8 v = *reinterpret_cast<const s16x8*>(&WcatT[(size_t)(n0 + n) * KP + k0 + bcol]);
      *reinterpret_cast<s16x8*>(&Bs[n][bcol]) = v;
    }
    __syncthreads();
#pragma unroll
    for (int ks = 0; ks < 2; ++ks) {
      const int kk = ks * 32 + (lane >> 4) * 8;
      s16x8 a[4], b[4];
#pragma unroll
      for (int m = 0; m < 4; ++m)
        a[m] = *reinterpret_cast<const s16x8*>(&As[wr * 64 + m * 16 + (lane & 15)][kk]);
#pragma unroll
      for (int n = 0; n < 4; ++n)
        b[n] = *reinterpret_cast<const s16x8*>(&Bs[wc * 64 + n * 16 + (lane & 15)][kk]);
#pragma unroll
      for (int m = 0; m < 4; ++m)
#pragma unroll
        for (int n = 0; n < 4; ++n)
          acc[m][n] = __builtin_amdgcn_mfma_f32_16x16x32_bf16(a[m], b[n], acc[m][n], 0, 0, 0);
    }
    __syncthreads();
  }
  const int fc = lane & 15;
  const int fr = (lane >> 4) * 4;
#pragma unroll
  for (int n = 0; n < 4; ++n) {
    int col = n0 + wc * 64 + n * 16 + fc;
    float bias = bcat[col];
#pragma unroll
    for (int m = 0; m < 4; ++m) {
#pragma unroll
      for (int r = 0; r < 4; ++r) {
        int row = m0 + wr * 64 + m * 16 + fr + r;
        C[(size_t)row * NG + col] = (_Float16)(acc[m][n][r] + bias);
      }
    }
  }
}

// One block (4 waves) per batch row, 1 block/CU — EXACT round-8 structure
// (218 us proven), with i2h and hs in f16 (halved HBM traffic; loads/stores
// stay scalar, deep quad prefetch unchanged).
__global__ __launch_bounds__(256, 4)
void rec_seq(
    const _Float16* __restrict__ i2h, const _Float16* __restrict__ Wg16,
    const float* __restrict__ h_in, const float* __restrict__ c_in,
    float* __restrict__ h_state, float* __restrict__ c_state,
    _Float16* __restrict__ hs_out, float* __restrict__ hT_out, float* __restrict__ cT_out,
    int T, int is_last) {
  const int b = blockIdx.x;
  const int tid = threadIdx.x;
  const int ww = tid >> 6;
  const int l = tid & 63;
  const int g = l >> 4;
  const int hidx = ww * 16 + (l & 15);
  const int col = g * 64 + hidx;

  // 32 KB raw LDS: stage weights [kk][col] (f16x8), then bytes [0..256) are
  // reused (ALIASED) as the double-buffered h. Remat past the overwrite would
  // be a miscompile -> weights must stay in VGPRs (r7/r8 verified VGPR 44-48).
  __shared__ __align__(16) char LB[8 * NG * 16];
  f16x8* Wst = reinterpret_cast<f16x8*>(LB);           // Wst[kk*256 + c]
  _Float16* hbuf = reinterpret_cast<_Float16*>(LB);    // hbuf[(s&1)*64 + hidx]

  for (int e = tid; e < 8 * NG; e += 256) {
    int kk = e >> 8, c = e & 255;
    Wst[e] = *reinterpret_cast<const f16x8*>(Wg16 + (size_t)c * NH + kk * 8);
  }
  __syncthreads();

  f16x8 w0 = Wst[0 * NG + col], w1 = Wst[1 * NG + col];
  f16x8 w2 = Wst[2 * NG + col], w3 = Wst[3 * NG + col];
  f16x8 w4 = Wst[4 * NG + col], w5 = Wst[5 * NG + col];
  f16x8 w6 = Wst[6 * NG + col], w7 = Wst[7 * NG + col];

  float creg = 0.f, hreg = 0.f;
  if (l < 16) creg = c_in[b * NH + hidx];
  float h0v = (tid < NH) ? h_in[b * NH + tid] : 0.f;
  __syncthreads();   // all weight reads done before the overwrite below

  if (tid < NH) hbuf[tid] = (_Float16)h0v;   // clobbers weight region
  __syncthreads();

  const size_t st = (size_t)NG * BATCH;      // i2h f16 elems per step
  const _Float16* ip = i2h + (size_t)b * NG + col;
  _Float16* hp = hs_out + (size_t)b * NH + hidx;
  const float mm = (g == 1) ? 2.f : 1.f;

#define PAIR(v, j) __builtin_shufflevector(v, v, 2*(j), 2*(j)+1)
#define DOT(hb, i, W) { f16x8 hv = (hb)[i]; \
      acc0 = __builtin_amdgcn_fdot2(PAIR(hv,0), PAIR(W,0), acc0, false); \
      acc1 = __builtin_amdgcn_fdot2(PAIR(hv,1), PAIR(W,1), acc1, false); \
      acc0 = __builtin_amdgcn_fdot2(PAIR(hv,2), PAIR(W,2), acc0, false); \
      acc1 = __builtin_amdgcn_fdot2(PAIR(hv,3), PAIR(W,3), acc1, false); }

#define STEP(CUR, SP) { \
    const f16x8* hb = reinterpret_cast<const f16x8*>(hbuf + ((SP) & 1) * NH); \
    float acc0 = 0.f, acc1 = 0.f; \
    DOT(hb, 0, w0) DOT(hb, 1, w1) DOT(hb, 2, w2) DOT(hb, 3, w3) \
    DOT(hb, 4, w4) DOT(hb, 5, w5) DOT(hb, 6, w6) DOT(hb, 7, w7) \
    float pre = (CUR) + (acc0 + acc1); \
    float xx = fminf(fmaxf(pre, -30.f), 30.f); \
    float e = __expf(-mm * xx); \
    float y = 1.f / (1.f + e); \
    float act = (g == 1) ? (2.f * y - 1.f) : y; \
    float g_ = __shfl(act, l + 16); \
    float i_ = __shfl(act, l + 32); \
    float o_ = __shfl(act, l + 48); \
    if (l < 16) { \
      float c1 = act * creg + i_ * g_; \
      creg = c1; \
      float ct = fminf(fmaxf(c1, -15.f), 15.f); \
      float e2 = __expf(-2.f * ct); \
      float th = (1.f - e2) / (1.f + e2); \
      float h1 = o_ * th; \
      hreg = h1; \
      hbuf[(((SP) + 1) & 1) * NH + hidx] = (_Float16)h1; \
      *hp = (_Float16)h1;  /* fire-and-forget */ \
    } \
    hp += st >> 2; /* BATCH*NH f16 per step */ \
    asm volatile("s_waitcnt lgkmcnt(0)" ::: "memory"); \
    __builtin_amdgcn_s_barrier(); }

  int s = 0;
  if (T >= 8) {
    float c0v = ip[0],      c1v = ip[st],     c2v = ip[2 * st], c3v = ip[3 * st];
    float n0v = ip[4 * st], n1v = ip[5 * st], n2v = ip[6 * st], n3v = ip[7 * st];
    const _Float16* ipf = ip + 8 * st;
    while (s + 4 <= T) {
      float f0v = (s + 8  < T) ? (float)ipf[0]      : 0.f;
      float f1v = (s + 9  < T) ? (float)ipf[st]     : 0.f;
      float f2v = (s + 10 < T) ? (float)ipf[2 * st] : 0.f;
      float f3v = (s + 11 < T) ? (float)ipf[3 * st] : 0.f;
      ipf += 4 * st;
      STEP(c0v, s)
      STEP(c1v, s + 1)
      STEP(c2v, s + 2)
      STEP(c3v, s + 3)
      c0v = n0v; c1v = n1v; c2v = n2v; c3v = n3v;   // waits: loads 1 quad old
      n0v = f0v; n1v = f1v; n2v = f2v; n3v = f3v;   // waits: loads this quad top
      s += 4;
    }
    if (s < T) { STEP(c0v, s) s++; }
    if (s < T) { STEP(c1v, s) s++; }
    if (s < T) { STEP(c2v, s) s++; }
  } else {
    while (s < T) { float cv = ip[(size_t)s * st]; STEP(cv, s) s++; }
  }

  if (l < 16) {
    h_state[b * NH + hidx] = hreg;
    c_state[b * NH + hidx] = creg;
    if (is_last) {
      hT_out[b * NH + hidx] = hreg;
      cT_out[b * NH + hidx] = creg;
    }
  }
}

// decoded[idx][j] = hs[idx][:] @ Wdec[:,j] + bdec[j], idx = s*BATCH+b
__global__ __launch_bounds__(256) void decode(
    const _Float16* __restrict__ hs, const float* __restrict__ Wdec,
    const float* __restrict__ bdec, float* __restrict__ out, int n) {
  __shared__ float wl[NH * 3];
  __shared__ float bl[3];
  const int tid = threadIdx.x;
  if (tid < NH * 3) wl[tid] = Wdec[tid];
  if (tid < 3) bl[tid] = bdec[tid];
  __syncthreads();
  int idx = blockIdx.x * 256 + tid;
  if (idx >= n) return;
  const _Float16* hp = hs + (size_t)idx * NH;
  float d0 = 0.f, d1 = 0.f, d2 = 0.f;
#pragma unroll
  for (int k = 0; k < NH; k += 4) {
    f16x4 h4 = *reinterpret_cast<const f16x4*>(&hp[k]);
#pragma unroll
    for (int j = 0; j < 4; ++j) {
      float hv = (float)h4[j];
      d0 += hv * wl[(k + j) * 3 + 0];
      d1 += hv * wl[(k + j) * 3 + 1];
      d2 += hv * wl[(k + j) * 3 + 2];
    }
  }
  out[(size_t)idx * 3 + 0] = d0 + bl[0];
  out[(size_t)idx * 3 + 1] = d1 + bl[1];
  out[(size_t)idx * 3 + 2] = d2 + bl[2];
}

extern "C" void kernel_launch(void* const* d_in, const int* in_sizes, int n_in,
                              void* d_out, int out_size, void* d_ws, size_t ws_size,
                              hipStream_t stream) {
  const float* x    = (const float*)d_in[0];
  const float* h0   = (const float*)d_in[1];
  const float* c0   = (const float*)d_in[2];
  const float* Wpt0 = (const float*)d_in[3];
  const float* bpt0 = (const float*)d_in[4];
  const float* Wpt1 = (const float*)d_in[5];
  const float* bpt1 = (const float*)d_in[6];
  const float* Wglt = (const float*)d_in[7];
  const float* Wdec = (const float*)d_in[8];
  const float* bdec = (const float*)d_in[9];
  float* out = (float*)d_out;

  char* ws = (char*)d_ws;
  short*     WcatT   = (short*)(ws);              // 163840 B
  float*     bcat    = (float*)(ws + 163840);     // 1 KB
  _Float16*  Wg16    = (_Float16*)(ws + 164864);  // 32768 B (256 x 64 f16)
  float*     h_state = (float*)(ws + 197632);     // 64 KB
  float*     c_state = (float*)(ws + 263168);     // 64 KB
  const size_t base = 328704;

  // per-step chunk bytes: i2h f16 (256*256*2) + hs f16 (256*64*2)
  const size_t i2h_step = (size_t)BATCH * NG * 2;
  const size_t hs_step  = (size_t)BATCH * NH * 2;
  size_t avail = (ws_size > base) ? ws_size - base : 0;
  int T = (int)(avail / (i2h_step + hs_step));
  if (T > SLEN) T = SLEN;
  if (T < 1) T = 1;

  _Float16* i2h = (_Float16*)(ws + base);
  _Float16* hs  = (_Float16*)(ws + base + (size_t)T * i2h_step);

  prep_w<<<dim3((NG * KP + 255) / 256), dim3(256), 0, stream>>>(
      Wpt0, bpt0, Wpt1, bpt1, Wglt, WcatT, bcat, Wg16);

  for (int t0 = 0; t0 < SLEN; t0 += T) {
    int Tc = (SLEN - t0 < T) ? (SLEN - t0) : T;
    dim3 g(NG / BN, Tc * BATCH / BM);   // N fast, M slow: x-slab L2 reuse
    gemm_i2h<<<g, dim3(256), 0, stream>>>(
        x + (size_t)t0 * BATCH * NIN, WcatT, bcat, i2h);
    rec_seq<<<dim3(BATCH), dim3(256), 0, stream>>>(
        i2h, Wg16,
        (t0 == 0) ? h0 : h_state, (t0 == 0) ? c0 : c_state,
        h_state, c_state, hs,
        out + (size_t)SLEN * BATCH * 3,
        out + (size_t)SLEN * BATCH * 3 + BATCH * NH,
        Tc, (t0 + Tc >= SLEN) ? 1 : 0);
    decode<<<dim3((Tc * BATCH + 255) / 256), dim3(256), 0, stream>>>(
        hs, Wdec, bdec, out + (size_t)t0 * BATCH * 3, Tc * BATCH);
  }
}

// Round 13
// 293.285 us; speedup vs baseline: 1.6951x; 1.3768x over previous
//
#include <hip/hip_runtime.h>
#include <hip/hip_bf16.h>

#define SLEN 512
#define BATCH 256
#define NIN 300
#define KP 320
#define NG 256
#define NH 64
#define BM 128
#define BN 128
#define BK 64
#define LDP 72   // padded LDS row length (bf16) -> 144B rows, 2-way (free) b128 reads

typedef float f32x4 __attribute__((ext_vector_type(4)));
typedef short s16x8 __attribute__((ext_vector_type(8)));
typedef short s16x4 __attribute__((ext_vector_type(4)));
typedef _Float16 f16x8 __attribute__((ext_vector_type(8)));
typedef _Float16 f16x4 __attribute__((ext_vector_type(4)));

__device__ __forceinline__ short f2bf(float f) {
  union { float f; unsigned u; } v; v.f = f;
  unsigned r = v.u + 0x7fffu + ((v.u >> 16) & 1u);  // RNE
  return (short)(r >> 16);
}

// Build WcatT[n][k] (bf16, K padded to 320), bcat[n], and Wg16[col][k] = f16(W_glt[k][col]).
__global__ void prep_w(const float* __restrict__ Wpt0, const float* __restrict__ bpt0,
                       const float* __restrict__ Wpt1, const float* __restrict__ bpt1,
                       const float* __restrict__ Wglt,
                       short* __restrict__ WcatT, float* __restrict__ bcat,
                       _Float16* __restrict__ Wg16) {
  int idx = blockIdx.x * 256 + threadIdx.x;
  if (idx < NG * KP) {
    int n = idx / KP, k = idx - n * KP;
    int g = n >> 6, h = n & 63;
    float w = 0.f;
    if (k < NIN) {
      if (h < 32) w = Wpt0[k * 128 + g * 32 + h];
      else        w = 0.5f * Wpt1[(k >> 1) * 128 + g * 32 + (h - 32)];
    }
    WcatT[idx] = f2bf(w);
  }
  if (idx < NG * NH) {  // transpose W_glt (64 x 256) -> Wg16 (256 x 64), f16
    int c = idx >> 6, k = idx & 63;
    Wg16[idx] = (_Float16)Wglt[k * NG + c];
  }
  if (idx < NG) {
    int g = idx >> 6, h = idx & 63;
    bcat[idx] = (h < 32) ? bpt0[g * 32 + h] : bpt1[g * 32 + h - 32];
  }
}

// C[row][n] = f16( bf16(x[row]) @ WcatT^T + bcat )
// grid = (2, M/BM): the two N-halves of one M-tile are dispatch-adjacent ->
// the second reads the x slab from L2 instead of HBM.
__global__ __launch_bounds__(256) void gemm_i2h(
    const float* __restrict__ x, const short* __restrict__ WcatT,
    const float* __restrict__ bcat, _Float16* __restrict__ C) {
  __shared__ short As[BM][LDP];
  __shared__ short Bs[BN][LDP];
  const int tid = threadIdx.x;
  const int m0 = blockIdx.y * BM;     // M on the slow axis
  const int n0 = blockIdx.x * BN;     // N-pair adjacent in dispatch order
  const int lane = tid & 63;
  const int w = tid >> 6;
  const int wr = w >> 1, wc = w & 1;

  f32x4 acc[4][4];
#pragma unroll
  for (int m = 0; m < 4; ++m)
#pragma unroll
    for (int n = 0; n < 4; ++n) acc[m][n] = (f32x4){0.f, 0.f, 0.f, 0.f};

  const int arow_l = tid >> 4;        // 0..15
  const int acol   = (tid & 15) * 4;  // 0..60
  const int brow_l = tid >> 3;        // 0..31
  const int bcol   = (tid & 7) * 8;   // 0..56

  for (int k0 = 0; k0 < KP; k0 += BK) {
#pragma unroll
    for (int p = 0; p < 8; ++p) {
      int row = p * 16 + arow_l;
      int gk = k0 + acol;
      f32x4 v = (f32x4){0.f, 0.f, 0.f, 0.f};
      if (gk + 3 < NIN)  // 300 = 4*75 so vectors never straddle the boundary
        v = *reinterpret_cast<const f32x4*>(&x[(size_t)(m0 + row) * NIN + gk]);
      s16x4 sv;
      sv[0] = f2bf(v[0]); sv[1] = f2bf(v[1]); sv[2] = f2bf(v[2]); sv[3] = f2bf(v[3]);
      *reinterpret_cast<s16x4*>(&As[row][acol]) = sv;
    }
#pragma unroll
    for (int p = 0; p < 4; ++p) {
      int n = p * 32 + brow_l;
      s16x8 v = *reinterpret_cast<const s16x8*>(&WcatT[(size_t)(n0 + n) * KP + k0 + bcol]);
      *reinterpret_cast<s16x8*>(&Bs[n][bcol]) = v;
    }
    __syncthreads();
#pragma unroll
    for (int ks = 0; ks < 2; ++ks) {
      const int kk = ks * 32 + (lane >> 4) * 8;
      s16x8 a[4], b[4];
#pragma unroll
      for (int m = 0; m < 4; ++m)
        a[m] = *reinterpret_cast<const s16x8*>(&As[wr * 64 + m * 16 + (lane & 15)][kk]);
#pragma unroll
      for (int n = 0; n < 4; ++n)
        b[n] = *reinterpret_cast<const s16x8*>(&Bs[wc * 64 + n * 16 + (lane & 15)][kk]);
#pragma unroll
      for (int m = 0; m < 4; ++m)
#pragma unroll
        for (int n = 0; n < 4; ++n)
          acc[m][n] = __builtin_amdgcn_mfma_f32_16x16x32_bf16(a[m], b[n], acc[m][n], 0, 0, 0);
    }
    __syncthreads();
  }
  const int fc = lane & 15;
  const int fr = (lane >> 4) * 4;
#pragma unroll
  for (int n = 0; n < 4; ++n) {
    int col = n0 + wc * 64 + n * 16 + fc;
    float bias = bcat[col];
#pragma unroll
    for (int m = 0; m < 4; ++m) {
#pragma unroll
      for (int r = 0; r < 4; ++r) {
        int row = m0 + wr * 64 + m * 16 + fr + r;
        C[(size_t)row * NG + col] = (_Float16)(acc[m][n][r] + bias);
      }
    }
  }
}

// One block (4 waves) per batch row — round-8 structure (218 us proven).
// i2h is f16, but the prefetch pipeline carries RAW USHORT registers:
// uniform-branch-guarded global_load_ushort (zero-extend, no d16 merge, no
// attached cvt) -> nothing reads the loaded reg until its STEP one quad
// later -> the compiler's s_waitcnt lands at the bottom, loads get ~2800 cyc
// (r12's (float) cast attached a v_cvt at the top = exposed HBM latency).
__global__ __launch_bounds__(256, 4)
void rec_seq(
    const _Float16* __restrict__ i2h, const _Float16* __restrict__ Wg16,
    const float* __restrict__ h_in, const float* __restrict__ c_in,
    float* __restrict__ h_state, float* __restrict__ c_state,
    _Float16* __restrict__ hs_out, float* __restrict__ hT_out, float* __restrict__ cT_out,
    int T, int is_last) {
  const int b = blockIdx.x;
  const int tid = threadIdx.x;
  const int ww = tid >> 6;
  const int l = tid & 63;
  const int g = l >> 4;
  const int hidx = ww * 16 + (l & 15);
  const int col = g * 64 + hidx;

  // 32 KB raw LDS: stage weights [kk][col] (f16x8), then bytes [0..256) are
  // reused (ALIASED) as the double-buffered h. Remat past the overwrite would
  // be a miscompile -> weights must stay in VGPRs (r7/r8 verified VGPR 44-48).
  __shared__ __align__(16) char LB[8 * NG * 16];
  f16x8* Wst = reinterpret_cast<f16x8*>(LB);           // Wst[kk*256 + c]
  _Float16* hbuf = reinterpret_cast<_Float16*>(LB);    // hbuf[(s&1)*64 + hidx]

  for (int e = tid; e < 8 * NG; e += 256) {
    int kk = e >> 8, c = e & 255;
    Wst[e] = *reinterpret_cast<const f16x8*>(Wg16 + (size_t)c * NH + kk * 8);
  }
  __syncthreads();

  f16x8 w0 = Wst[0 * NG + col], w1 = Wst[1 * NG + col];
  f16x8 w2 = Wst[2 * NG + col], w3 = Wst[3 * NG + col];
  f16x8 w4 = Wst[4 * NG + col], w5 = Wst[5 * NG + col];
  f16x8 w6 = Wst[6 * NG + col], w7 = Wst[7 * NG + col];

  float creg = 0.f, hreg = 0.f;
  if (l < 16) creg = c_in[b * NH + hidx];
  float h0v = (tid < NH) ? h_in[b * NH + tid] : 0.f;
  __syncthreads();   // all weight reads done before the overwrite below

  if (tid < NH) hbuf[tid] = (_Float16)h0v;   // clobbers weight region
  __syncthreads();

  const size_t st = (size_t)NG * BATCH;      // i2h f16 elems per step
  const unsigned short* ip =
      reinterpret_cast<const unsigned short*>(i2h) + (size_t)b * NG + col;
  _Float16* hp = hs_out + (size_t)b * NH + hidx;
  const float mm = (g == 1) ? 2.f : 1.f;

#define PAIR(v, j) __builtin_shufflevector(v, v, 2*(j), 2*(j)+1)
#define DOT(hb, i, W) { f16x8 hv = (hb)[i]; \
      acc0 = __builtin_amdgcn_fdot2(PAIR(hv,0), PAIR(W,0), acc0, false); \
      acc1 = __builtin_amdgcn_fdot2(PAIR(hv,1), PAIR(W,1), acc1, false); \
      acc0 = __builtin_amdgcn_fdot2(PAIR(hv,2), PAIR(W,2), acc0, false); \
      acc1 = __builtin_amdgcn_fdot2(PAIR(hv,3), PAIR(W,3), acc1, false); }

#define STEP(CUR, SP) { \
    float cur_ = (float)__builtin_bit_cast(_Float16, (unsigned short)(CUR)); \
    const f16x8* hb = reinterpret_cast<const f16x8*>(hbuf + ((SP) & 1) * NH); \
    float acc0 = 0.f, acc1 = 0.f; \
    DOT(hb, 0, w0) DOT(hb, 1, w1) DOT(hb, 2, w2) DOT(hb, 3, w3) \
    DOT(hb, 4, w4) DOT(hb, 5, w5) DOT(hb, 6, w6) DOT(hb, 7, w7) \
    float pre = cur_ + (acc0 + acc1); \
    float xx = fminf(fmaxf(pre, -30.f), 30.f); \
    float e = __expf(-mm * xx); \
    float y = 1.f / (1.f + e); \
    float act = (g == 1) ? (2.f * y - 1.f) : y; \
    float g_ = __shfl(act, l + 16); \
    float i_ = __shfl(act, l + 32); \
    float o_ = __shfl(act, l + 48); \
    if (l < 16) { \
      float c1 = act * creg + i_ * g_; \
      creg = c1; \
      float ct = fminf(fmaxf(c1, -15.f), 15.f); \
      float e2 = __expf(-2.f * ct); \
      float th = (1.f - e2) / (1.f + e2); \
      float h1 = o_ * th; \
      hreg = h1; \
      hbuf[(((SP) + 1) & 1) * NH + hidx] = (_Float16)h1; \
      *hp = (_Float16)h1;  /* fire-and-forget */ \
    } \
    hp += st >> 2; /* BATCH*NH f16 per step */ \
    asm volatile("s_waitcnt lgkmcnt(0)" ::: "memory"); \
    __builtin_amdgcn_s_barrier(); }

  int s = 0;
  if (T >= 8) {
    unsigned short c0v = ip[0],      c1v = ip[st],     c2v = ip[2 * st], c3v = ip[3 * st];
    unsigned short n0v = ip[4 * st], n1v = ip[5 * st], n2v = ip[6 * st], n3v = ip[7 * st];
    const unsigned short* ipf = ip + 8 * st;
    while (s + 4 <= T) {
      unsigned short f0v = 0, f1v = 0, f2v = 0, f3v = 0;
      if (s + 8  < T) f0v = ipf[0];        // uniform branch; nothing reads
      if (s + 9  < T) f1v = ipf[st];       // the reg until STEP next quad
      if (s + 10 < T) f2v = ipf[2 * st];
      if (s + 11 < T) f3v = ipf[3 * st];
      ipf += 4 * st;
      STEP(c0v, s)
      STEP(c1v, s + 1)
      STEP(c2v, s + 2)
      STEP(c3v, s + 3)
      c0v = n0v; c1v = n1v; c2v = n2v; c3v = n3v;   // waits: loads 1 quad old
      n0v = f0v; n1v = f1v; n2v = f2v; n3v = f3v;   // waits: loads this quad top
      s += 4;
    }
    if (s < T) { STEP(c0v, s) s++; }
    if (s < T) { STEP(c1v, s) s++; }
    if (s < T) { STEP(c2v, s) s++; }
  } else {
    while (s < T) { unsigned short cv = ip[(size_t)s * st]; STEP(cv, s) s++; }
  }

  if (l < 16) {
    h_state[b * NH + hidx] = hreg;
    c_state[b * NH + hidx] = creg;
    if (is_last) {
      hT_out[b * NH + hidx] = hreg;
      cT_out[b * NH + hidx] = creg;
    }
  }
}

// decoded[idx][j] = hs[idx][:] @ Wdec[:,j] + bdec[j], idx = s*BATCH+b
__global__ __launch_bounds__(256) void decode(
    const _Float16* __restrict__ hs, const float* __restrict__ Wdec,
    const float* __restrict__ bdec, float* __restrict__ out, int n) {
  __shared__ float wl[NH * 3];
  __shared__ float bl[3];
  const int tid = threadIdx.x;
  if (tid < NH * 3) wl[tid] = Wdec[tid];
  if (tid < 3) bl[tid] = bdec[tid];
  __syncthreads();
  int idx = blockIdx.x * 256 + tid;
  if (idx >= n) return;
  const _Float16* hp = hs + (size_t)idx * NH;
  float d0 = 0.f, d1 = 0.f, d2 = 0.f;
#pragma unroll
  for (int k = 0; k < NH; k += 4) {
    f16x4 h4 = *reinterpret_cast<const f16x4*>(&hp[k]);
#pragma unroll
    for (int j = 0; j < 4; ++j) {
      float hv = (float)h4[j];
      d0 += hv * wl[(k + j) * 3 + 0];
      d1 += hv * wl[(k + j) * 3 + 1];
      d2 += hv * wl[(k + j) * 3 + 2];
    }
  }
  out[(size_t)idx * 3 + 0] = d0 + bl[0];
  out[(size_t)idx * 3 + 1] = d1 + bl[1];
  out[(size_t)idx * 3 + 2] = d2 + bl[2];
}

extern "C" void kernel_launch(void* const* d_in, const int* in_sizes, int n_in,
                              void* d_out, int out_size, void* d_ws, size_t ws_size,
                              hipStream_t stream) {
  const float* x    = (const float*)d_in[0];
  const float* h0   = (const float*)d_in[1];
  const float* c0   = (const float*)d_in[2];
  const float* Wpt0 = (const float*)d_in[3];
  const float* bpt0 = (const float*)d_in[4];
  const float* Wpt1 = (const float*)d_in[5];
  const float* bpt1 = (const float*)d_in[6];
  const float* Wglt = (const float*)d_in[7];
  const float* Wdec = (const float*)d_in[8];
  const float* bdec = (const float*)d_in[9];
  float* out = (float*)d_out;

  char* ws = (char*)d_ws;
  short*     WcatT   = (short*)(ws);              // 163840 B
  float*     bcat    = (float*)(ws + 163840);     // 1 KB
  _Float16*  Wg16    = (_Float16*)(ws + 164864);  // 32768 B (256 x 64 f16)
  float*     h_state = (float*)(ws + 197632);     // 64 KB
  float*     c_state = (float*)(ws + 263168);     // 64 KB
  const size_t base = 328704;

  // per-step chunk bytes: i2h f16 (256*256*2) + hs f16 (256*64*2)
  const size_t i2h_step = (size_t)BATCH * NG * 2;
  const size_t hs_step  = (size_t)BATCH * NH * 2;
  size_t avail = (ws_size > base) ? ws_size - base : 0;
  int T = (int)(avail / (i2h_step + hs_step));
  if (T > SLEN) T = SLEN;
  if (T < 1) T = 1;

  _Float16* i2h = (_Float16*)(ws + base);
  _Float16* hs  = (_Float16*)(ws + base + (size_t)T * i2h_step);

  prep_w<<<dim3((NG * KP + 255) / 256), dim3(256), 0, stream>>>(
      Wpt0, bpt0, Wpt1, bpt1, Wglt, WcatT, bcat, Wg16);

  for (int t0 = 0; t0 < SLEN; t0 += T) {
    int Tc = (SLEN - t0 < T) ? (SLEN - t0) : T;
    dim3 g(NG / BN, Tc * BATCH / BM);   // N fast, M slow: x-slab L2 reuse
    gemm_i2h<<<g, dim3(256), 0, stream>>>(
        x + (size_t)t0 * BATCH * NIN, WcatT, bcat, i2h);
    rec_seq<<<dim3(BATCH), dim3(256), 0, stream>>>(
        i2h, Wg16,
        (t0 == 0) ? h0 : h_state, (t0 == 0) ? c0 : c_state,
        h_state, c_state, hs,
        out + (size_t)SLEN * BATCH * 3,
        out + (size_t)SLEN * BATCH * 3 + BATCH * NH,
        Tc, (t0 + Tc >= SLEN) ? 1 : 0);
    decode<<<dim3((Tc * BATCH + 255) / 256), dim3(256), 0, stream>>>(
        hs, Wdec, bdec, out + (size_t)t0 * BATCH * 3, Tc * BATCH);
  }
}

// Round 14
// 293.029 us; speedup vs baseline: 1.6965x; 1.0009x over previous
//
#include <hip/hip_runtime.h>
#include <hip/hip_bf16.h>

#define SLEN 512
#define BATCH 256
#define NIN 300
#define KP 320
#define NG 256
#define NH 64
#define BM 128
#define BN 128
#define BK 64
#define LDP 72   // padded LDS row length (f16) -> 144B rows, 2-way (free) b128 reads

typedef float f32x4 __attribute__((ext_vector_type(4)));
typedef _Float16 f16x8 __attribute__((ext_vector_type(8)));
typedef _Float16 f16x4 __attribute__((ext_vector_type(4)));

// Build Wc16[n][k] (f16, K padded to 320), bcat[n], and Wg16[col][k] = f16(W_glt[k][col]).
__global__ void prep_w(const float* __restrict__ Wpt0, const float* __restrict__ bpt0,
                       const float* __restrict__ Wpt1, const float* __restrict__ bpt1,
                       const float* __restrict__ Wglt,
                       _Float16* __restrict__ Wc16, float* __restrict__ bcat,
                       _Float16* __restrict__ Wg16) {
  int idx = blockIdx.x * 256 + threadIdx.x;
  if (idx < NG * KP) {
    int n = idx / KP, k = idx - n * KP;
    int g = n >> 6, h = n & 63;
    float w = 0.f;
    if (k < NIN) {
      if (h < 32) w = Wpt0[k * 128 + g * 32 + h];
      else        w = 0.5f * Wpt1[(k >> 1) * 128 + g * 32 + (h - 32)];
    }
    Wc16[idx] = (_Float16)w;
  }
  if (idx < NG * NH) {  // transpose W_glt (64 x 256) -> Wg16 (256 x 64), f16
    int c = idx >> 6, k = idx & 63;
    Wg16[idx] = (_Float16)Wglt[k * NG + c];
  }
  if (idx < NG) {
    int g = idx >> 6, h = idx & 63;
    bcat[idx] = (h < 32) ? bpt0[g * 32 + h] : bpt1[g * 32 + h - 32];
  }
}

// C[row][n] = f16( f16(x[row]) @ Wc16^T + bcat )
// All-f16 pipeline: A staged via v_cvt_f16_f32 (6 VALU / 4 values, vs ~64 for
// manual bf16 RNE — staging was the gemm bottleneck), mfma f16 (same rate).
// grid = (2, M/BM): N-pair dispatch-adjacent -> x slab L2 reuse.
__global__ __launch_bounds__(256) void gemm_i2h(
    const float* __restrict__ x, const _Float16* __restrict__ Wc16,
    const float* __restrict__ bcat, _Float16* __restrict__ C) {
  __shared__ _Float16 As[BM][LDP];
  __shared__ _Float16 Bs[BN][LDP];
  const int tid = threadIdx.x;
  const int m0 = blockIdx.y * BM;     // M on the slow axis
  const int n0 = blockIdx.x * BN;     // N-pair adjacent in dispatch order
  const int lane = tid & 63;
  const int w = tid >> 6;
  const int wr = w >> 1, wc = w & 1;

  f32x4 acc[4][4];
#pragma unroll
  for (int m = 0; m < 4; ++m)
#pragma unroll
    for (int n = 0; n < 4; ++n) acc[m][n] = (f32x4){0.f, 0.f, 0.f, 0.f};

  const int arow_l = tid >> 4;        // 0..15
  const int acol   = (tid & 15) * 4;  // 0..60
  const int brow_l = tid >> 3;        // 0..31
  const int bcol   = (tid & 7) * 8;   // 0..56

  for (int k0 = 0; k0 < KP; k0 += BK) {
#pragma unroll
    for (int p = 0; p < 8; ++p) {
      int row = p * 16 + arow_l;
      int gk = k0 + acol;
      f32x4 v = (f32x4){0.f, 0.f, 0.f, 0.f};
      if (gk + 3 < NIN)  // 300 = 4*75 so vectors never straddle the boundary
        v = *reinterpret_cast<const f32x4*>(&x[(size_t)(m0 + row) * NIN + gk]);
      f16x4 sv;
      sv[0] = (_Float16)v[0]; sv[1] = (_Float16)v[1];
      sv[2] = (_Float16)v[2]; sv[3] = (_Float16)v[3];
      *reinterpret_cast<f16x4*>(&As[row][acol]) = sv;
    }
#pragma unroll
    for (int p = 0; p < 4; ++p) {
      int n = p * 32 + brow_l;
      f16x8 v = *reinterpret_cast<const f16x8*>(&Wc16[(size_t)(n0 + n) * KP + k0 + bcol]);
      *reinterpret_cast<f16x8*>(&Bs[n][bcol]) = v;
    }
    __syncthreads();
#pragma unroll
    for (int ks = 0; ks < 2; ++ks) {
      const int kk = ks * 32 + (lane >> 4) * 8;
      f16x8 a[4], b[4];
#pragma unroll
      for (int m = 0; m < 4; ++m)
        a[m] = *reinterpret_cast<const f16x8*>(&As[wr * 64 + m * 16 + (lane & 15)][kk]);
#pragma unroll
      for (int n = 0; n < 4; ++n)
        b[n] = *reinterpret_cast<const f16x8*>(&Bs[wc * 64 + n * 16 + (lane & 15)][kk]);
#pragma unroll
      for (int m = 0; m < 4; ++m)
#pragma unroll
        for (int n = 0; n < 4; ++n)
          acc[m][n] = __builtin_amdgcn_mfma_f32_16x16x32_f16(a[m], b[n], acc[m][n], 0, 0, 0);
    }
    __syncthreads();
  }
  const int fc = lane & 15;
  const int fr = (lane >> 4) * 4;
#pragma unroll
  for (int n = 0; n < 4; ++n) {
    int col = n0 + wc * 64 + n * 16 + fc;
    float bias = bcat[col];
#pragma unroll
    for (int m = 0; m < 4; ++m) {
#pragma unroll
      for (int r = 0; r < 4; ++r) {
        int row = m0 + wr * 64 + m * 16 + fr + r;
        C[(size_t)row * NG + col] = (_Float16)(acc[m][n][r] + bias);
      }
    }
  }
}

// One block (4 waves) per batch row — round-8/13 structure (218 us proven),
// UNCHANGED this round. i2h f16 with raw-ushort prefetch pipeline (r13).
__global__ __launch_bounds__(256, 4)
void rec_seq(
    const _Float16* __restrict__ i2h, const _Float16* __restrict__ Wg16,
    const float* __restrict__ h_in, const float* __restrict__ c_in,
    float* __restrict__ h_state, float* __restrict__ c_state,
    _Float16* __restrict__ hs_out, float* __restrict__ hT_out, float* __restrict__ cT_out,
    int T, int is_last) {
  const int b = blockIdx.x;
  const int tid = threadIdx.x;
  const int ww = tid >> 6;
  const int l = tid & 63;
  const int g = l >> 4;
  const int hidx = ww * 16 + (l & 15);
  const int col = g * 64 + hidx;

  // 32 KB raw LDS: stage weights [kk][col] (f16x8), then bytes [0..256) are
  // reused (ALIASED) as the double-buffered h. Remat past the overwrite would
  // be a miscompile -> weights must stay in VGPRs (r7/r8/r13 verified).
  __shared__ __align__(16) char LB[8 * NG * 16];
  f16x8* Wst = reinterpret_cast<f16x8*>(LB);           // Wst[kk*256 + c]
  _Float16* hbuf = reinterpret_cast<_Float16*>(LB);    // hbuf[(s&1)*64 + hidx]

  for (int e = tid; e < 8 * NG; e += 256) {
    int kk = e >> 8, c = e & 255;
    Wst[e] = *reinterpret_cast<const f16x8*>(Wg16 + (size_t)c * NH + kk * 8);
  }
  __syncthreads();

  f16x8 w0 = Wst[0 * NG + col], w1 = Wst[1 * NG + col];
  f16x8 w2 = Wst[2 * NG + col], w3 = Wst[3 * NG + col];
  f16x8 w4 = Wst[4 * NG + col], w5 = Wst[5 * NG + col];
  f16x8 w6 = Wst[6 * NG + col], w7 = Wst[7 * NG + col];

  float creg = 0.f, hreg = 0.f;
  if (l < 16) creg = c_in[b * NH + hidx];
  float h0v = (tid < NH) ? h_in[b * NH + tid] : 0.f;
  __syncthreads();   // all weight reads done before the overwrite below

  if (tid < NH) hbuf[tid] = (_Float16)h0v;   // clobbers weight region
  __syncthreads();

  const size_t st = (size_t)NG * BATCH;      // i2h f16 elems per step
  const unsigned short* ip =
      reinterpret_cast<const unsigned short*>(i2h) + (size_t)b * NG + col;
  _Float16* hp = hs_out + (size_t)b * NH + hidx;
  const float mm = (g == 1) ? 2.f : 1.f;

#define PAIR(v, j) __builtin_shufflevector(v, v, 2*(j), 2*(j)+1)
#define DOT(hb, i, W) { f16x8 hv = (hb)[i]; \
      acc0 = __builtin_amdgcn_fdot2(PAIR(hv,0), PAIR(W,0), acc0, false); \
      acc1 = __builtin_amdgcn_fdot2(PAIR(hv,1), PAIR(W,1), acc1, false); \
      acc0 = __builtin_amdgcn_fdot2(PAIR(hv,2), PAIR(W,2), acc0, false); \
      acc1 = __builtin_amdgcn_fdot2(PAIR(hv,3), PAIR(W,3), acc1, false); }

#define STEP(CUR, SP) { \
    float cur_ = (float)__builtin_bit_cast(_Float16, (unsigned short)(CUR)); \
    const f16x8* hb = reinterpret_cast<const f16x8*>(hbuf + ((SP) & 1) * NH); \
    float acc0 = 0.f, acc1 = 0.f; \
    DOT(hb, 0, w0) DOT(hb, 1, w1) DOT(hb, 2, w2) DOT(hb, 3, w3) \
    DOT(hb, 4, w4) DOT(hb, 5, w5) DOT(hb, 6, w6) DOT(hb, 7, w7) \
    float pre = cur_ + (acc0 + acc1); \
    float xx = fminf(fmaxf(pre, -30.f), 30.f); \
    float e = __expf(-mm * xx); \
    float y = 1.f / (1.f + e); \
    float act = (g == 1) ? (2.f * y - 1.f) : y; \
    float g_ = __shfl(act, l + 16); \
    float i_ = __shfl(act, l + 32); \
    float o_ = __shfl(act, l + 48); \
    if (l < 16) { \
      float c1 = act * creg + i_ * g_; \
      creg = c1; \
      float ct = fminf(fmaxf(c1, -15.f), 15.f); \
      float e2 = __expf(-2.f * ct); \
      float th = (1.f - e2) / (1.f + e2); \
      float h1 = o_ * th; \
      hreg = h1; \
      hbuf[(((SP) + 1) & 1) * NH + hidx] = (_Float16)h1; \
      *hp = (_Float16)h1;  /* fire-and-forget */ \
    } \
    hp += st >> 2; /* BATCH*NH f16 per step */ \
    asm volatile("s_waitcnt lgkmcnt(0)" ::: "memory"); \
    __builtin_amdgcn_s_barrier(); }

  int s = 0;
  if (T >= 8) {
    unsigned short c0v = ip[0],      c1v = ip[st],     c2v = ip[2 * st], c3v = ip[3 * st];
    unsigned short n0v = ip[4 * st], n1v = ip[5 * st], n2v = ip[6 * st], n3v = ip[7 * st];
    const unsigned short* ipf = ip + 8 * st;
    while (s + 4 <= T) {
      unsigned short f0v = 0, f1v = 0, f2v = 0, f3v = 0;
      if (s + 8  < T) f0v = ipf[0];        // uniform branch; nothing reads
      if (s + 9  < T) f1v = ipf[st];       // the reg until STEP next quad
      if (s + 10 < T) f2v = ipf[2 * st];
      if (s + 11 < T) f3v = ipf[3 * st];
      ipf += 4 * st;
      STEP(c0v, s)
      STEP(c1v, s + 1)
      STEP(c2v, s + 2)
      STEP(c3v, s + 3)
      c0v = n0v; c1v = n1v; c2v = n2v; c3v = n3v;   // waits: loads 1 quad old
      n0v = f0v; n1v = f1v; n2v = f2v; n3v = f3v;   // waits: loads this quad top
      s += 4;
    }
    if (s < T) { STEP(c0v, s) s++; }
    if (s < T) { STEP(c1v, s) s++; }
    if (s < T) { STEP(c2v, s) s++; }
  } else {
    while (s < T) { unsigned short cv = ip[(size_t)s * st]; STEP(cv, s) s++; }
  }

  if (l < 16) {
    h_state[b * NH + hidx] = hreg;
    c_state[b * NH + hidx] = creg;
    if (is_last) {
      hT_out[b * NH + hidx] = hreg;
      cT_out[b * NH + hidx] = creg;
    }
  }
}

// decoded[idx][j] = hs[idx][:] @ Wdec[:,j] + bdec[j], idx = s*BATCH+b
// Outputs staged in LDS, flushed as 192 coalesced f32x4 stores per block
// (was 12B/thread strided). grid is exact: n = Tc*BATCH is a multiple of 256.
__global__ __launch_bounds__(256) void decode(
    const _Float16* __restrict__ hs, const float* __restrict__ Wdec,
    const float* __restrict__ bdec, float* __restrict__ out) {
  __shared__ float wl[NH * 3];
  __shared__ float bl[3];
  __shared__ float ob[256 * 3];
  const int tid = threadIdx.x;
  if (tid < NH * 3) wl[tid] = Wdec[tid];
  if (tid < 3) bl[tid] = bdec[tid];
  __syncthreads();
  const size_t idx = (size_t)blockIdx.x * 256 + tid;
  const _Float16* hp = hs + idx * NH;
  float d0 = 0.f, d1 = 0.f, d2 = 0.f;
#pragma unroll
  for (int k = 0; k < NH; k += 8) {
    f16x8 h8 = *reinterpret_cast<const f16x8*>(&hp[k]);
#pragma unroll
    for (int j = 0; j < 8; ++j) {
      float hv = (float)h8[j];
      d0 += hv * wl[(k + j) * 3 + 0];
      d1 += hv * wl[(k + j) * 3 + 1];
      d2 += hv * wl[(k + j) * 3 + 2];
    }
  }
  ob[tid * 3 + 0] = d0 + bl[0];
  ob[tid * 3 + 1] = d1 + bl[1];
  ob[tid * 3 + 2] = d2 + bl[2];
  __syncthreads();
  if (tid < 192) {
    f32x4* o4 = reinterpret_cast<f32x4*>(out + (size_t)blockIdx.x * 768);
    o4[tid] = reinterpret_cast<const f32x4*>(ob)[tid];
  }
}

extern "C" void kernel_launch(void* const* d_in, const int* in_sizes, int n_in,
                              void* d_out, int out_size, void* d_ws, size_t ws_size,
                              hipStream_t stream) {
  const float* x    = (const float*)d_in[0];
  const float* h0   = (const float*)d_in[1];
  const float* c0   = (const float*)d_in[2];
  const float* Wpt0 = (const float*)d_in[3];
  const float* bpt0 = (const float*)d_in[4];
  const float* Wpt1 = (const float*)d_in[5];
  const float* bpt1 = (const float*)d_in[6];
  const float* Wglt = (const float*)d_in[7];
  const float* Wdec = (const float*)d_in[8];
  const float* bdec = (const float*)d_in[9];
  float* out = (float*)d_out;

  char* ws = (char*)d_ws;
  _Float16*  Wc16    = (_Float16*)(ws);           // 163840 B
  float*     bcat    = (float*)(ws + 163840);     // 1 KB
  _Float16*  Wg16    = (_Float16*)(ws + 164864);  // 32768 B (256 x 64 f16)
  float*     h_state = (float*)(ws + 197632);     // 64 KB
  float*     c_state = (float*)(ws + 263168);     // 64 KB
  const size_t base = 328704;

  // per-step chunk bytes: i2h f16 (256*256*2) + hs f16 (256*64*2)
  const size_t i2h_step = (size_t)BATCH * NG * 2;
  const size_t hs_step  = (size_t)BATCH * NH * 2;
  size_t avail = (ws_size > base) ? ws_size - base : 0;
  int T = (int)(avail / (i2h_step + hs_step));
  if (T > SLEN) T = SLEN;
  if (T < 1) T = 1;

  _Float16* i2h = (_Float16*)(ws + base);
  _Float16* hs  = (_Float16*)(ws + base + (size_t)T * i2h_step);

  prep_w<<<dim3((NG * KP + 255) / 256), dim3(256), 0, stream>>>(
      Wpt0, bpt0, Wpt1, bpt1, Wglt, Wc16, bcat, Wg16);

  for (int t0 = 0; t0 < SLEN; t0 += T) {
    int Tc = (SLEN - t0 < T) ? (SLEN - t0) : T;
    dim3 g(NG / BN, Tc * BATCH / BM);   // N fast, M slow: x-slab L2 reuse
    gemm_i2h<<<g, dim3(256), 0, stream>>>(
        x + (size_t)t0 * BATCH * NIN, Wc16, bcat, i2h);
    rec_seq<<<dim3(BATCH), dim3(256), 0, stream>>>(
        i2h, Wg16,
        (t0 == 0) ? h0 : h_state, (t0 == 0) ? c0 : c_state,
        h_state, c_state, hs,
        out + (size_t)SLEN * BATCH * 3,
        out + (size_t)SLEN * BATCH * 3 + BATCH * NH,
        Tc, (t0 + Tc >= SLEN) ? 1 : 0);
    decode<<<dim3(Tc * BATCH / 256), dim3(256), 0, stream>>>(
        hs, Wdec, bdec, out + (size_t)t0 * BATCH * 3);
  }
}

// Round 15
// 276.892 us; speedup vs baseline: 1.7954x; 1.0583x over previous
//
#include <hip/hip_runtime.h>
#include <hip/hip_bf16.h>

#define SLEN 512
#define BATCH 256
#define NIN 300
#define KP 320
#define NG 256
#define NH 64
#define BM 128
#define BN 128
#define BK 64
#define LDP 72   // padded LDS row length (f16) -> 144B rows, 2-way (free) b128 reads
#define TC 128   // steps per chunk
#define NCH (SLEN / TC)

typedef float f32x4 __attribute__((ext_vector_type(4)));
typedef _Float16 f16x8 __attribute__((ext_vector_type(8)));
typedef _Float16 f16x4 __attribute__((ext_vector_type(4)));

// Build Wc16[n][k] (f16, K padded to 320), bcat[n], and Wg16[col][k] = f16(W_glt[k][col]).
__global__ void prep_w(const float* __restrict__ Wpt0, const float* __restrict__ bpt0,
                       const float* __restrict__ Wpt1, const float* __restrict__ bpt1,
                       const float* __restrict__ Wglt,
                       _Float16* __restrict__ Wc16, float* __restrict__ bcat,
                       _Float16* __restrict__ Wg16) {
  int idx = blockIdx.x * 256 + threadIdx.x;
  if (idx < NG * KP) {
    int n = idx / KP, k = idx - n * KP;
    int g = n >> 6, h = n & 63;
    float w = 0.f;
    if (k < NIN) {
      if (h < 32) w = Wpt0[k * 128 + g * 32 + h];
      else        w = 0.5f * Wpt1[(k >> 1) * 128 + g * 32 + (h - 32)];
    }
    Wc16[idx] = (_Float16)w;
  }
  if (idx < NG * NH) {  // transpose W_glt (64 x 256) -> Wg16 (256 x 64), f16
    int c = idx >> 6, k = idx & 63;
    Wg16[idx] = (_Float16)Wglt[k * NG + c];
  }
  if (idx < NG) {
    int g = idx >> 6, h = idx & 63;
    bcat[idx] = (h < 32) ? bpt0[g * 32 + h] : bpt1[g * 32 + h - 32];
  }
}

// ---------------- shared device bodies (used by standalone + fused) ----------

__device__ __forceinline__ void gemm_body(
    char* LB, int m0, int n0, int tid,
    const float* __restrict__ x, const _Float16* __restrict__ Wc16,
    const float* __restrict__ bcat, _Float16* __restrict__ C) {
  _Float16 (*As)[LDP] = reinterpret_cast<_Float16(*)[LDP]>(LB);
  _Float16 (*Bs)[LDP] = reinterpret_cast<_Float16(*)[LDP]>(LB + BM * LDP * 2);
  const int lane = tid & 63;
  const int w = tid >> 6;
  const int wr = w >> 1, wc = w & 1;

  f32x4 acc[4][4];
#pragma unroll
  for (int m = 0; m < 4; ++m)
#pragma unroll
    for (int n = 0; n < 4; ++n) acc[m][n] = (f32x4){0.f, 0.f, 0.f, 0.f};

  const int arow_l = tid >> 4;        // 0..15
  const int acol   = (tid & 15) * 4;  // 0..60
  const int brow_l = tid >> 3;        // 0..31
  const int bcol   = (tid & 7) * 8;   // 0..56

  for (int k0 = 0; k0 < KP; k0 += BK) {
#pragma unroll
    for (int p = 0; p < 8; ++p) {
      int row = p * 16 + arow_l;
      int gk = k0 + acol;
      f32x4 v = (f32x4){0.f, 0.f, 0.f, 0.f};
      if (gk + 3 < NIN)  // 300 = 4*75: vectors never straddle the boundary
        v = *reinterpret_cast<const f32x4*>(&x[(size_t)(m0 + row) * NIN + gk]);
      f16x4 sv;
      sv[0] = (_Float16)v[0]; sv[1] = (_Float16)v[1];
      sv[2] = (_Float16)v[2]; sv[3] = (_Float16)v[3];
      *reinterpret_cast<f16x4*>(&As[row][acol]) = sv;
    }
#pragma unroll
    for (int p = 0; p < 4; ++p) {
      int n = p * 32 + brow_l;
      f16x8 v = *reinterpret_cast<const f16x8*>(&Wc16[(size_t)(n0 + n) * KP + k0 + bcol]);
      *reinterpret_cast<f16x8*>(&Bs[n][bcol]) = v;
    }
    __syncthreads();
#pragma unroll
    for (int ks = 0; ks < 2; ++ks) {
      const int kk = ks * 32 + (lane >> 4) * 8;
      f16x8 a[4], b[4];
#pragma unroll
      for (int m = 0; m < 4; ++m)
        a[m] = *reinterpret_cast<const f16x8*>(&As[wr * 64 + m * 16 + (lane & 15)][kk]);
#pragma unroll
      for (int n = 0; n < 4; ++n)
        b[n] = *reinterpret_cast<const f16x8*>(&Bs[wc * 64 + n * 16 + (lane & 15)][kk]);
#pragma unroll
      for (int m = 0; m < 4; ++m)
#pragma unroll
        for (int n = 0; n < 4; ++n)
          acc[m][n] = __builtin_amdgcn_mfma_f32_16x16x32_f16(a[m], b[n], acc[m][n], 0, 0, 0);
    }
    __syncthreads();
  }
  const int fc = lane & 15;
  const int fr = (lane >> 4) * 4;
#pragma unroll
  for (int n = 0; n < 4; ++n) {
    int col = n0 + wc * 64 + n * 16 + fc;
    float bias = bcat[col];
#pragma unroll
    for (int m = 0; m < 4; ++m) {
#pragma unroll
      for (int r = 0; r < 4; ++r) {
        int row = m0 + wr * 64 + m * 16 + fr + r;
        C[(size_t)row * NG + col] = (_Float16)(acc[m][n][r] + bias);
      }
    }
  }
}

__device__ __forceinline__ void decode_body(
    char* LB, int blk, int tid,
    const _Float16* __restrict__ hs, const float* __restrict__ Wdec,
    const float* __restrict__ bdec, float* __restrict__ out) {
  float* wl = reinterpret_cast<float*>(LB);          // 768 B
  float* bl = reinterpret_cast<float*>(LB + 768);    // 12 B
  float* ob = reinterpret_cast<float*>(LB + 784);    // 3072 B
  if (tid < NH * 3) wl[tid] = Wdec[tid];
  if (tid < 3) bl[tid] = bdec[tid];
  __syncthreads();
  const size_t idx = (size_t)blk * 256 + tid;
  const _Float16* hp = hs + idx * NH;
  float d0 = 0.f, d1 = 0.f, d2 = 0.f;
#pragma unroll
  for (int k = 0; k < NH; k += 8) {
    f16x8 h8 = *reinterpret_cast<const f16x8*>(&hp[k]);
#pragma unroll
    for (int j = 0; j < 8; ++j) {
      float hv = (float)h8[j];
      d0 += hv * wl[(k + j) * 3 + 0];
      d1 += hv * wl[(k + j) * 3 + 1];
      d2 += hv * wl[(k + j) * 3 + 2];
    }
  }
  ob[tid * 3 + 0] = d0 + bl[0];
  ob[tid * 3 + 1] = d1 + bl[1];
  ob[tid * 3 + 2] = d2 + bl[2];
  __syncthreads();
  if (tid < 192) {
    f32x4* o4 = reinterpret_cast<f32x4*>(out + (size_t)blk * 768);
    o4[tid] = reinterpret_cast<const f32x4*>(ob)[tid];
  }
}

// rec-step macros (r13 proven)
#define PAIR(v, j) __builtin_shufflevector(v, v, 2*(j), 2*(j)+1)
#define DOT(hb, i, W) { f16x8 hv = (hb)[i]; \
      acc0 = __builtin_amdgcn_fdot2(PAIR(hv,0), PAIR(W,0), acc0, false); \
      acc1 = __builtin_amdgcn_fdot2(PAIR(hv,1), PAIR(W,1), acc1, false); \
      acc0 = __builtin_amdgcn_fdot2(PAIR(hv,2), PAIR(W,2), acc0, false); \
      acc1 = __builtin_amdgcn_fdot2(PAIR(hv,3), PAIR(W,3), acc1, false); }

#define STEP(CUR, SP) { \
    float cur_ = (float)__builtin_bit_cast(_Float16, (unsigned short)(CUR)); \
    const f16x8* hb = reinterpret_cast<const f16x8*>(hbuf + ((SP) & 1) * NH); \
    float acc0 = 0.f, acc1 = 0.f; \
    DOT(hb, 0, w0) DOT(hb, 1, w1) DOT(hb, 2, w2) DOT(hb, 3, w3) \
    DOT(hb, 4, w4) DOT(hb, 5, w5) DOT(hb, 6, w6) DOT(hb, 7, w7) \
    float pre = cur_ + (acc0 + acc1); \
    float xx = fminf(fmaxf(pre, -30.f), 30.f); \
    float e = __expf(-mm * xx); \
    float y = 1.f / (1.f + e); \
    float act = (g == 1) ? (2.f * y - 1.f) : y; \
    float g_ = __shfl(act, l + 16); \
    float i_ = __shfl(act, l + 32); \
    float o_ = __shfl(act, l + 48); \
    if (l < 16) { \
      float c1 = act * creg + i_ * g_; \
      creg = c1; \
      float ct = fminf(fmaxf(c1, -15.f), 15.f); \
      float e2 = __expf(-2.f * ct); \
      float th = (1.f - e2) / (1.f + e2); \
      float h1 = o_ * th; \
      hreg = h1; \
      hbuf[(((SP) + 1) & 1) * NH + hidx] = (_Float16)h1; \
      *hp = (_Float16)h1;  /* fire-and-forget */ \
    } \
    hp += st >> 2; /* BATCH*NH f16 per step */ \
    asm volatile("s_waitcnt lgkmcnt(0)" ::: "memory"); \
    __builtin_amdgcn_s_barrier(); }

// ---------------- standalone kernels (chunk 0 gemm, final decode) ------------

__global__ __launch_bounds__(256, 2) void gemm_i2h(
    const float* __restrict__ x, const _Float16* __restrict__ Wc16,
    const float* __restrict__ bcat, _Float16* __restrict__ C) {
  __shared__ __align__(16) char LB[36864];
  gemm_body(LB, blockIdx.y * BM, blockIdx.x * BN, threadIdx.x, x, Wc16, bcat, C);
}

__global__ __launch_bounds__(256) void decode(
    const _Float16* __restrict__ hs, const float* __restrict__ Wdec,
    const float* __restrict__ bdec, float* __restrict__ out) {
  __shared__ __align__(16) char LB[4096];
  decode_body(LB, blockIdx.x, threadIdx.x, hs, Wdec, bdec, out);
}

// ---------------- fused chunk kernel ----------------------------------------
// bid < 256            : rec for chunk k (r13 body, 1 block/row, 4 waves)
// bid < 256+512 (gemm) : i2h GEMM for chunk k+1 (rides in rec's shadow)
// rest (dec)           : decode of chunk k-1
// rec blocks have the lowest indices -> dispatched first, one per CU.
__global__ __launch_bounds__(256, 2)
void fused_step(
    const _Float16* __restrict__ i2h_cur, _Float16* __restrict__ i2h_next,
    const float* __restrict__ x_next,
    const _Float16* __restrict__ Wc16, const float* __restrict__ bcat,
    const _Float16* __restrict__ Wg16,
    const float* __restrict__ h_in, const float* __restrict__ c_in,
    float* __restrict__ h_state, float* __restrict__ c_state,
    _Float16* __restrict__ hs_cur, const _Float16* __restrict__ hs_prev,
    const float* __restrict__ Wdec, const float* __restrict__ bdec,
    float* __restrict__ out_prev,
    float* __restrict__ hT_out, float* __restrict__ cT_out,
    int is_last, int has_gemm) {
  __shared__ __align__(16) char LB[36864];
  const int bid = blockIdx.x;
  const int tid = threadIdx.x;

  if (bid < BATCH) {
    // ------------------ rec role (r13 byte-equivalent, T = TC) --------------
    const int b = bid;
    const int ww = tid >> 6;
    const int l = tid & 63;
    const int g = l >> 4;
    const int hidx = ww * 16 + (l & 15);
    const int col = g * 64 + hidx;

    f16x8* Wst = reinterpret_cast<f16x8*>(LB);           // Wst[kk*256 + c]
    _Float16* hbuf = reinterpret_cast<_Float16*>(LB);    // hbuf[(s&1)*64 + hidx]

    for (int e = tid; e < 8 * NG; e += 256) {
      int kk = e >> 8, c = e & 255;
      Wst[e] = *reinterpret_cast<const f16x8*>(Wg16 + (size_t)c * NH + kk * 8);
    }
    __syncthreads();

    f16x8 w0 = Wst[0 * NG + col], w1 = Wst[1 * NG + col];
    f16x8 w2 = Wst[2 * NG + col], w3 = Wst[3 * NG + col];
    f16x8 w4 = Wst[4 * NG + col], w5 = Wst[5 * NG + col];
    f16x8 w6 = Wst[6 * NG + col], w7 = Wst[7 * NG + col];

    float creg = 0.f, hreg = 0.f;
    if (l < 16) creg = c_in[b * NH + hidx];
    float h0v = (tid < NH) ? h_in[b * NH + tid] : 0.f;
    __syncthreads();   // all weight reads done before the overwrite below

    if (tid < NH) hbuf[tid] = (_Float16)h0v;   // clobbers weight region
    __syncthreads();

    const size_t st = (size_t)NG * BATCH;      // i2h f16 elems per step
    const unsigned short* ip =
        reinterpret_cast<const unsigned short*>(i2h_cur) + (size_t)b * NG + col;
    _Float16* hp = hs_cur + (size_t)b * NH + hidx;
    const float mm = (g == 1) ? 2.f : 1.f;

    int s = 0;
    {
      unsigned short c0v = ip[0],      c1v = ip[st],     c2v = ip[2 * st], c3v = ip[3 * st];
      unsigned short n0v = ip[4 * st], n1v = ip[5 * st], n2v = ip[6 * st], n3v = ip[7 * st];
      const unsigned short* ipf = ip + 8 * st;
      while (s + 4 <= TC) {
        unsigned short f0v = 0, f1v = 0, f2v = 0, f3v = 0;
        if (s + 8  < TC) f0v = ipf[0];        // uniform branch; nothing reads
        if (s + 9  < TC) f1v = ipf[st];       // the reg until STEP next quad
        if (s + 10 < TC) f2v = ipf[2 * st];
        if (s + 11 < TC) f3v = ipf[3 * st];
        ipf += 4 * st;
        STEP(c0v, s)
        STEP(c1v, s + 1)
        STEP(c2v, s + 2)
        STEP(c3v, s + 3)
        c0v = n0v; c1v = n1v; c2v = n2v; c3v = n3v;   // waits: loads 1 quad old
        n0v = f0v; n1v = f1v; n2v = f2v; n3v = f3v;   // waits: loads this quad top
        s += 4;
      }
    }

    if (l < 16) {
      h_state[b * NH + hidx] = hreg;
      c_state[b * NH + hidx] = creg;
      if (is_last) {
        hT_out[b * NH + hidx] = hreg;
        cT_out[b * NH + hidx] = creg;
      }
    }
  } else if (has_gemm && bid < BATCH + 2 * (TC * BATCH / BM)) {
    // ------------------ gemm role: i2h for chunk k+1 ------------------------
    const int gid = bid - BATCH;
    const int n0 = (gid & 1) * BN;      // N-pair adjacent -> x slab L2 reuse
    const int m0 = (gid >> 1) * BM;
    gemm_body(LB, m0, n0, tid, x_next, Wc16, bcat, i2h_next);
  } else {
    // ------------------ decode role: chunk k-1 ------------------------------
    const int did = bid - BATCH - (has_gemm ? 2 * (TC * BATCH / BM) : 0);
    decode_body(LB, did, tid, hs_prev, Wdec, bdec, out_prev);
  }
}

extern "C" void kernel_launch(void* const* d_in, const int* in_sizes, int n_in,
                              void* d_out, int out_size, void* d_ws, size_t ws_size,
                              hipStream_t stream) {
  const float* x    = (const float*)d_in[0];
  const float* h0   = (const float*)d_in[1];
  const float* c0   = (const float*)d_in[2];
  const float* Wpt0 = (const float*)d_in[3];
  const float* bpt0 = (const float*)d_in[4];
  const float* Wpt1 = (const float*)d_in[5];
  const float* bpt1 = (const float*)d_in[6];
  const float* Wglt = (const float*)d_in[7];
  const float* Wdec = (const float*)d_in[8];
  const float* bdec = (const float*)d_in[9];
  float* out = (float*)d_out;

  char* ws = (char*)d_ws;
  _Float16*  Wc16    = (_Float16*)(ws);           // 163840 B
  float*     bcat    = (float*)(ws + 163840);     // 1 KB
  _Float16*  Wg16    = (_Float16*)(ws + 164864);  // 32768 B (256 x 64 f16)
  float*     h_state = (float*)(ws + 197632);     // 64 KB
  float*     c_state = (float*)(ws + 263168);     // 64 KB
  const size_t base = 328704;

  const size_t chunk_i2h = (size_t)TC * BATCH * NG;     // f16 elems per chunk
  _Float16* i2h0 = (_Float16*)(ws + base);
  _Float16* i2h1 = i2h0 + chunk_i2h;
  _Float16* hs   = (_Float16*)(ws + base + 4 * chunk_i2h);  // 2 bufs * 2 B

  prep_w<<<dim3((NG * KP + 255) / 256), dim3(256), 0, stream>>>(
      Wpt0, bpt0, Wpt1, bpt1, Wglt, Wc16, bcat, Wg16);

  // chunk 0 GEMM (full GPU, nothing to overlap with yet)
  gemm_i2h<<<dim3(2, TC * BATCH / BM), dim3(256), 0, stream>>>(
      x, Wc16, bcat, i2h0);

  for (int k = 0; k < NCH; ++k) {
    _Float16* cur = (k & 1) ? i2h1 : i2h0;
    _Float16* nxt = (k & 1) ? i2h0 : i2h1;
    const int has_gemm = (k + 1 < NCH) ? 1 : 0;
    const int has_dec  = (k > 0) ? 1 : 0;
    const int nblk = BATCH + (has_gemm ? 2 * (TC * BATCH / BM) : 0)
                           + (has_dec ? (TC * BATCH / 256) : 0);
    const int kp = (k > 0) ? (k - 1) : 0;
    fused_step<<<dim3(nblk), dim3(256), 0, stream>>>(
        cur, nxt, x + (size_t)(k + 1) * TC * BATCH * NIN,
        Wc16, bcat, Wg16,
        (k == 0) ? h0 : h_state, (k == 0) ? c0 : c_state,
        h_state, c_state,
        hs + (size_t)k * TC * BATCH * NH,
        hs + (size_t)kp * TC * BATCH * NH,
        Wdec, bdec,
        out + (size_t)kp * TC * BATCH * 3,
        out + (size_t)SLEN * BATCH * 3,
        out + (size_t)SLEN * BATCH * 3 + BATCH * NH,
        (k == NCH - 1) ? 1 : 0, has_gemm);
  }

  // decode of the last chunk
  decode<<<dim3(TC * BATCH / 256), dim3(256), 0, stream>>>(
      hs + (size_t)(NCH - 1) * TC * BATCH * NH, Wdec, bdec,
      out + (size_t)(NCH - 1) * TC * BATCH * 3);
}

// Round 16
// 247.967 us; speedup vs baseline: 2.0048x; 1.1166x over previous
//
#include <hip/hip_runtime.h>
#include <hip/hip_bf16.h>

#define SLEN 512
#define BATCH 256
#define NIN 300
#define KP 320
#define NG 256
#define NH 64
#define BM 128
#define BN 128
#define BK 64
#define LDP 72   // padded LDS row length (f16) -> 144B rows, 2-way (free) b128 reads
#define TC 128   // steps per chunk
#define NCH (SLEN / TC)

typedef float f32x4 __attribute__((ext_vector_type(4)));
typedef _Float16 f16x8 __attribute__((ext_vector_type(8)));
typedef _Float16 f16x4 __attribute__((ext_vector_type(4)));

// quad-lane broadcast via DPP quad_perm [J,J,J,J] — VALU-speed cross-lane
template <int J>
__device__ __forceinline__ float quad_bcast(float v) {
  return __builtin_bit_cast(float,
      __builtin_amdgcn_mov_dpp(__builtin_bit_cast(int, v),
                               J * 0x55, 0xf, 0xf, true));
}

// Build Wc16[n][k] (f16, K padded to 320), bcat[n], and Wg16[col][k] = f16(W_glt[k][col]).
__global__ void prep_w(const float* __restrict__ Wpt0, const float* __restrict__ bpt0,
                       const float* __restrict__ Wpt1, const float* __restrict__ bpt1,
                       const float* __restrict__ Wglt,
                       _Float16* __restrict__ Wc16, float* __restrict__ bcat,
                       _Float16* __restrict__ Wg16) {
  int idx = blockIdx.x * 256 + threadIdx.x;
  if (idx < NG * KP) {
    int n = idx / KP, k = idx - n * KP;
    int g = n >> 6, h = n & 63;
    float w = 0.f;
    if (k < NIN) {
      if (h < 32) w = Wpt0[k * 128 + g * 32 + h];
      else        w = 0.5f * Wpt1[(k >> 1) * 128 + g * 32 + (h - 32)];
    }
    Wc16[idx] = (_Float16)w;
  }
  if (idx < NG * NH) {  // transpose W_glt (64 x 256) -> Wg16 (256 x 64), f16
    int c = idx >> 6, k = idx & 63;
    Wg16[idx] = (_Float16)Wglt[k * NG + c];
  }
  if (idx < NG) {
    int g = idx >> 6, h = idx & 63;
    bcat[idx] = (h < 32) ? bpt0[g * 32 + h] : bpt1[g * 32 + h - 32];
  }
}

// ---------------- shared device bodies (used by standalone + fused) ----------

__device__ __forceinline__ void gemm_body(
    char* LB, int m0, int n0, int tid,
    const float* __restrict__ x, const _Float16* __restrict__ Wc16,
    const float* __restrict__ bcat, _Float16* __restrict__ C) {
  _Float16 (*As)[LDP] = reinterpret_cast<_Float16(*)[LDP]>(LB);
  _Float16 (*Bs)[LDP] = reinterpret_cast<_Float16(*)[LDP]>(LB + BM * LDP * 2);
  const int lane = tid & 63;
  const int w = tid >> 6;
  const int wr = w >> 1, wc = w & 1;

  f32x4 acc[4][4];
#pragma unroll
  for (int m = 0; m < 4; ++m)
#pragma unroll
    for (int n = 0; n < 4; ++n) acc[m][n] = (f32x4){0.f, 0.f, 0.f, 0.f};

  const int arow_l = tid >> 4;        // 0..15
  const int acol   = (tid & 15) * 4;  // 0..60
  const int brow_l = tid >> 3;        // 0..31
  const int bcol   = (tid & 7) * 8;   // 0..56

  for (int k0 = 0; k0 < KP; k0 += BK) {
#pragma unroll
    for (int p = 0; p < 8; ++p) {
      int row = p * 16 + arow_l;
      int gk = k0 + acol;
      f32x4 v = (f32x4){0.f, 0.f, 0.f, 0.f};
      if (gk + 3 < NIN)  // 300 = 4*75: vectors never straddle the boundary
        v = *reinterpret_cast<const f32x4*>(&x[(size_t)(m0 + row) * NIN + gk]);
      f16x4 sv;
      sv[0] = (_Float16)v[0]; sv[1] = (_Float16)v[1];
      sv[2] = (_Float16)v[2]; sv[3] = (_Float16)v[3];
      *reinterpret_cast<f16x4*>(&As[row][acol]) = sv;
    }
#pragma unroll
    for (int p = 0; p < 4; ++p) {
      int n = p * 32 + brow_l;
      f16x8 v = *reinterpret_cast<const f16x8*>(&Wc16[(size_t)(n0 + n) * KP + k0 + bcol]);
      *reinterpret_cast<f16x8*>(&Bs[n][bcol]) = v;
    }
    __syncthreads();
#pragma unroll
    for (int ks = 0; ks < 2; ++ks) {
      const int kk = ks * 32 + (lane >> 4) * 8;
      f16x8 a[4], b[4];
#pragma unroll
      for (int m = 0; m < 4; ++m)
        a[m] = *reinterpret_cast<const f16x8*>(&As[wr * 64 + m * 16 + (lane & 15)][kk]);
#pragma unroll
      for (int n = 0; n < 4; ++n)
        b[n] = *reinterpret_cast<const f16x8*>(&Bs[wc * 64 + n * 16 + (lane & 15)][kk]);
#pragma unroll
      for (int m = 0; m < 4; ++m)
#pragma unroll
        for (int n = 0; n < 4; ++n)
          acc[m][n] = __builtin_amdgcn_mfma_f32_16x16x32_f16(a[m], b[n], acc[m][n], 0, 0, 0);
    }
    __syncthreads();
  }
  const int fc = lane & 15;
  const int fr = (lane >> 4) * 4;
#pragma unroll
  for (int n = 0; n < 4; ++n) {
    int col = n0 + wc * 64 + n * 16 + fc;
    float bias = bcat[col];
#pragma unroll
    for (int m = 0; m < 4; ++m) {
#pragma unroll
      for (int r = 0; r < 4; ++r) {
        int row = m0 + wr * 64 + m * 16 + fr + r;
        C[(size_t)row * NG + col] = (_Float16)(acc[m][n][r] + bias);
      }
    }
  }
}

__device__ __forceinline__ void decode_body(
    char* LB, int blk, int tid,
    const _Float16* __restrict__ hs, const float* __restrict__ Wdec,
    const float* __restrict__ bdec, float* __restrict__ out) {
  float* wl = reinterpret_cast<float*>(LB);          // 768 B
  float* bl = reinterpret_cast<float*>(LB + 768);    // 12 B
  float* ob = reinterpret_cast<float*>(LB + 784);    // 3072 B
  if (tid < NH * 3) wl[tid] = Wdec[tid];
  if (tid < 3) bl[tid] = bdec[tid];
  __syncthreads();
  const size_t idx = (size_t)blk * 256 + tid;
  const _Float16* hp = hs + idx * NH;
  float d0 = 0.f, d1 = 0.f, d2 = 0.f;
#pragma unroll
  for (int k = 0; k < NH; k += 8) {
    f16x8 h8 = *reinterpret_cast<const f16x8*>(&hp[k]);
#pragma unroll
    for (int j = 0; j < 8; ++j) {
      float hv = (float)h8[j];
      d0 += hv * wl[(k + j) * 3 + 0];
      d1 += hv * wl[(k + j) * 3 + 1];
      d2 += hv * wl[(k + j) * 3 + 2];
    }
  }
  ob[tid * 3 + 0] = d0 + bl[0];
  ob[tid * 3 + 1] = d1 + bl[1];
  ob[tid * 3 + 2] = d2 + bl[2];
  __syncthreads();
  if (tid < 192) {
    f32x4* o4 = reinterpret_cast<f32x4*>(out + (size_t)blk * 768);
    o4[tid] = reinterpret_cast<const f32x4*>(ob)[tid];
  }
}

// rec-step macros: quad-layout (lane = unit*4 + gate), DPP gate exchange
#define PAIR(v, j) __builtin_shufflevector(v, v, 2*(j), 2*(j)+1)
#define DOT(hb, i, W) { f16x8 hv = (hb)[i]; \
      acc0 = __builtin_amdgcn_fdot2(PAIR(hv,0), PAIR(W,0), acc0, false); \
      acc1 = __builtin_amdgcn_fdot2(PAIR(hv,1), PAIR(W,1), acc1, false); \
      acc0 = __builtin_amdgcn_fdot2(PAIR(hv,2), PAIR(W,2), acc0, false); \
      acc1 = __builtin_amdgcn_fdot2(PAIR(hv,3), PAIR(W,3), acc1, false); }

#define STEP(CUR, SP) { \
    float cur_ = (float)__builtin_bit_cast(_Float16, (unsigned short)(CUR)); \
    const f16x8* hb = reinterpret_cast<const f16x8*>(hbuf + ((SP) & 1) * NH); \
    float acc0 = 0.f, acc1 = 0.f; \
    DOT(hb, 0, w0) DOT(hb, 1, w1) DOT(hb, 2, w2) DOT(hb, 3, w3) \
    DOT(hb, 4, w4) DOT(hb, 5, w5) DOT(hb, 6, w6) DOT(hb, 7, w7) \
    float pre = cur_ + (acc0 + acc1); \
    float xx = fminf(fmaxf(pre, -30.f), 30.f); \
    float e = __expf(-mm * xx); \
    float y = 1.f / (1.f + e); \
    float act = (qid == 1) ? (2.f * y - 1.f) : y; \
    float f_ = quad_bcast<0>(act); \
    float g_ = quad_bcast<1>(act); \
    float i_ = quad_bcast<2>(act); \
    float o_ = quad_bcast<3>(act); \
    float c1 = f_ * creg + i_ * g_;   /* all 4 quad lanes, redundant */ \
    creg = c1; \
    float ct = fminf(fmaxf(c1, -15.f), 15.f); \
    float e2 = __expf(-2.f * ct); \
    float th = (1.f - e2) / (1.f + e2); \
    float h1 = o_ * th; \
    hreg = h1; \
    if (qid == 0) { \
      hbuf[(((SP) + 1) & 1) * NH + unit] = (_Float16)h1; \
      *hp = (_Float16)h1;  /* fire-and-forget */ \
    } \
    hp += st >> 2; /* BATCH*NH f16 per step */ \
    asm volatile("s_waitcnt lgkmcnt(0)" ::: "memory"); \
    __builtin_amdgcn_s_barrier(); }

// ---------------- standalone kernels (chunk 0 gemm, final decode) ------------

__global__ __launch_bounds__(256, 2) void gemm_i2h(
    const float* __restrict__ x, const _Float16* __restrict__ Wc16,
    const float* __restrict__ bcat, _Float16* __restrict__ C) {
  __shared__ __align__(16) char LB[36864];
  gemm_body(LB, blockIdx.y * BM, blockIdx.x * BN, threadIdx.x, x, Wc16, bcat, C);
}

__global__ __launch_bounds__(256) void decode(
    const _Float16* __restrict__ hs, const float* __restrict__ Wdec,
    const float* __restrict__ bdec, float* __restrict__ out) {
  __shared__ __align__(16) char LB[4096];
  decode_body(LB, blockIdx.x, threadIdx.x, hs, Wdec, bdec, out);
}

// ---------------- fused chunk kernel ----------------------------------------
// bid < 256            : rec for chunk k (quad-layout, 1 block/row, 4 waves)
// bid < 256+512 (gemm) : i2h GEMM for chunk k+1 (rides in rec's shadow)
// rest (dec)           : decode of chunk k-1
// rec blocks have the lowest indices -> dispatched first, one per CU.
__global__ __launch_bounds__(256, 2)
void fused_step(
    const _Float16* __restrict__ i2h_cur, _Float16* __restrict__ i2h_next,
    const float* __restrict__ x_next,
    const _Float16* __restrict__ Wc16, const float* __restrict__ bcat,
    const _Float16* __restrict__ Wg16,
    const float* __restrict__ h_in, const float* __restrict__ c_in,
    float* __restrict__ h_state, float* __restrict__ c_state,
    _Float16* __restrict__ hs_cur, const _Float16* __restrict__ hs_prev,
    const float* __restrict__ Wdec, const float* __restrict__ bdec,
    float* __restrict__ out_prev,
    float* __restrict__ hT_out, float* __restrict__ cT_out,
    int is_last, int has_gemm) {
  __shared__ __align__(16) char LB[36864];
  const int bid = blockIdx.x;
  const int tid = threadIdx.x;

  if (bid < BATCH) {
    // ------------------ rec role (quad layout, T = TC) ----------------------
    const int b = bid;
    const int ww = tid >> 6;
    const int l = tid & 63;
    const int qid = l & 3;              // gate index within quad
    const int unit = ww * 16 + (l >> 2);
    const int col = qid * 64 + unit;    // gate column in [0,256)

    f16x8* Wst = reinterpret_cast<f16x8*>(LB);           // Wst[kk*256 + c]
    _Float16* hbuf = reinterpret_cast<_Float16*>(LB);    // hbuf[(s&1)*64 + u]

    for (int e = tid; e < 8 * NG; e += 256) {
      int kk = e >> 8, c = e & 255;
      Wst[e] = *reinterpret_cast<const f16x8*>(Wg16 + (size_t)c * NH + kk * 8);
    }
    __syncthreads();

    f16x8 w0 = Wst[0 * NG + col], w1 = Wst[1 * NG + col];
    f16x8 w2 = Wst[2 * NG + col], w3 = Wst[3 * NG + col];
    f16x8 w4 = Wst[4 * NG + col], w5 = Wst[5 * NG + col];
    f16x8 w6 = Wst[6 * NG + col], w7 = Wst[7 * NG + col];

    float creg = c_in[b * NH + unit];   // replicated per quad, deterministic
    float hreg = 0.f;
    float h0v = (tid < NH) ? h_in[b * NH + tid] : 0.f;
    __syncthreads();   // all weight reads done before the overwrite below

    if (tid < NH) hbuf[tid] = (_Float16)h0v;   // clobbers weight region
    __syncthreads();

    const size_t st = (size_t)NG * BATCH;      // i2h f16 elems per step
    const unsigned short* ip =
        reinterpret_cast<const unsigned short*>(i2h_cur) + (size_t)b * NG + col;
    _Float16* hp = hs_cur + (size_t)b * NH + unit;
    const float mm = (qid == 1) ? 2.f : 1.f;

    int s = 0;
    {
      unsigned short c0v = ip[0],      c1v = ip[st],     c2v = ip[2 * st], c3v = ip[3 * st];
      unsigned short n0v = ip[4 * st], n1v = ip[5 * st], n2v = ip[6 * st], n3v = ip[7 * st];
      const unsigned short* ipf = ip + 8 * st;
      while (s + 4 <= TC) {
        unsigned short f0v = 0, f1v = 0, f2v = 0, f3v = 0;
        if (s + 8  < TC) f0v = ipf[0];        // uniform branch; nothing reads
        if (s + 9  < TC) f1v = ipf[st];       // the reg until STEP next quad
        if (s + 10 < TC) f2v = ipf[2 * st];
        if (s + 11 < TC) f3v = ipf[3 * st];
        ipf += 4 * st;
        STEP(c0v, s)
        STEP(c1v, s + 1)
        STEP(c2v, s + 2)
        STEP(c3v, s + 3)
        c0v = n0v; c1v = n1v; c2v = n2v; c3v = n3v;   // waits: loads 1 quad old
        n0v = f0v; n1v = f1v; n2v = f2v; n3v = f3v;   // waits: loads this quad top
        s += 4;
      }
    }

    if (qid == 0) {
      h_state[b * NH + unit] = hreg;
      c_state[b * NH + unit] = creg;
      if (is_last) {
        hT_out[b * NH + unit] = hreg;
        cT_out[b * NH + unit] = creg;
      }
    }
  } else if (has_gemm && bid < BATCH + 2 * (TC * BATCH / BM)) {
    // ------------------ gemm role: i2h for chunk k+1 ------------------------
    const int gid = bid - BATCH;
    const int n0 = (gid & 1) * BN;      // N-pair adjacent -> x slab L2 reuse
    const int m0 = (gid >> 1) * BM;
    gemm_body(LB, m0, n0, tid, x_next, Wc16, bcat, i2h_next);
  } else {
    // ------------------ decode role: chunk k-1 ------------------------------
    const int did = bid - BATCH - (has_gemm ? 2 * (TC * BATCH / BM) : 0);
    decode_body(LB, did, tid, hs_prev, Wdec, bdec, out_prev);
  }
}

extern "C" void kernel_launch(void* const* d_in, const int* in_sizes, int n_in,
                              void* d_out, int out_size, void* d_ws, size_t ws_size,
                              hipStream_t stream) {
  const float* x    = (const float*)d_in[0];
  const float* h0   = (const float*)d_in[1];
  const float* c0   = (const float*)d_in[2];
  const float* Wpt0 = (const float*)d_in[3];
  const float* bpt0 = (const float*)d_in[4];
  const float* Wpt1 = (const float*)d_in[5];
  const float* bpt1 = (const float*)d_in[6];
  const float* Wglt = (const float*)d_in[7];
  const float* Wdec = (const float*)d_in[8];
  const float* bdec = (const float*)d_in[9];
  float* out = (float*)d_out;

  char* ws = (char*)d_ws;
  _Float16*  Wc16    = (_Float16*)(ws);           // 163840 B
  float*     bcat    = (float*)(ws + 163840);     // 1 KB
  _Float16*  Wg16    = (_Float16*)(ws + 164864);  // 32768 B (256 x 64 f16)
  float*     h_state = (float*)(ws + 197632);     // 64 KB
  float*     c_state = (float*)(ws + 263168);     // 64 KB
  const size_t base = 328704;

  const size_t chunk_i2h = (size_t)TC * BATCH * NG;     // f16 elems per chunk
  _Float16* i2h0 = (_Float16*)(ws + base);
  _Float16* i2h1 = i2h0 + chunk_i2h;
  _Float16* hs   = (_Float16*)(ws + base + 4 * chunk_i2h);  // 2 bufs * 2 B

  prep_w<<<dim3((NG * KP + 255) / 256), dim3(256), 0, stream>>>(
      Wpt0, bpt0, Wpt1, bpt1, Wglt, Wc16, bcat, Wg16);

  // chunk 0 GEMM (full GPU, nothing to overlap with yet)
  gemm_i2h<<<dim3(2, TC * BATCH / BM), dim3(256), 0, stream>>>(
      x, Wc16, bcat, i2h0);

  for (int k = 0; k < NCH; ++k) {
    _Float16* cur = (k & 1) ? i2h1 : i2h0;
    _Float16* nxt = (k & 1) ? i2h0 : i2h1;
    const int has_gemm = (k + 1 < NCH) ? 1 : 0;
    const int has_dec  = (k > 0) ? 1 : 0;
    const int nblk = BATCH + (has_gemm ? 2 * (TC * BATCH / BM) : 0)
                           + (has_dec ? (TC * BATCH / 256) : 0);
    const int kp = (k > 0) ? (k - 1) : 0;
    fused_step<<<dim3(nblk), dim3(256), 0, stream>>>(
        cur, nxt, x + (size_t)(k + 1) * TC * BATCH * NIN,
        Wc16, bcat, Wg16,
        (k == 0) ? h0 : h_state, (k == 0) ? c0 : c_state,
        h_state, c_state,
        hs + (size_t)k * TC * BATCH * NH,
        hs + (size_t)kp * TC * BATCH * NH,
        Wdec, bdec,
        out + (size_t)kp * TC * BATCH * 3,
        out + (size_t)SLEN * BATCH * 3,
        out + (size_t)SLEN * BATCH * 3 + BATCH * NH,
        (k == NCH - 1) ? 1 : 0, has_gemm);
  }

  // decode of the last chunk
  decode<<<dim3(TC * BATCH / 256), dim3(256), 0, stream>>>(
      hs + (size_t)(NCH - 1) * TC * BATCH * NH, Wdec, bdec,
      out + (size_t)(NCH - 1) * TC * BATCH * 3);
}